// Round 13
// baseline (355.513 us; speedup 1.0000x reference)
//
#include <hip/hip_runtime.h>

typedef __bf16 bf16x8 __attribute__((ext_vector_type(8)));
typedef float f32x4 __attribute__((ext_vector_type(4)));

typedef __attribute__((address_space(1))) void gvoid;
typedef __attribute__((address_space(3))) void lvoid;

__device__ __forceinline__ void gl_lds16(const void* g, void* l) {
    __builtin_amdgcn_global_load_lds((gvoid*)g, (lvoid*)l, 16, 0, 0);
}

// NaN/inf scrub for epilogues only.
__device__ __forceinline__ float fin(float v) {
    v = (v == v) ? v : 0.f;
    return fminf(fmaxf(v, -3.0e38f), 3.0e38f);
}

__device__ __forceinline__ bf16x8 cvt8(float4 a, float4 b) {
    bf16x8 r;
    r[0] = (__bf16)a.x; r[1] = (__bf16)a.y; r[2] = (__bf16)a.z; r[3] = (__bf16)a.w;
    r[4] = (__bf16)b.x; r[5] = (__bf16)b.y; r[6] = (__bf16)b.z; r[7] = (__bf16)b.w;
    return r;
}

__device__ __forceinline__ void cvt_range(const float* __restrict__ in,
                                          __bf16* __restrict__ out, int i) {
    const float4* p = (const float4*)in + (size_t)i * 2;
    ((bf16x8*)out)[i] = cvt8(p[0], p[1]);
}

#define SCALE_LOG2E 0.12751666797152713f

// ---------------------------------------------------------------------------
// prep: fused cvt(x)+gate, cvt(w_qkv), rope table. (unchanged from round 8)
// ---------------------------------------------------------------------------
__global__ __launch_bounds__(256) void prep_kernel(const float* __restrict__ x,
                                                   const float* __restrict__ wqkv,
                                                   __bf16* __restrict__ xb,
                                                   __bf16* __restrict__ wqb,
                                                   const float* __restrict__ wg,
                                                   const float* __restrict__ bg,
                                                   float* __restrict__ gate,
                                                   float2* __restrict__ ropet) {
    __shared__ float gp[4][16];
    int bid = blockIdx.x, tid = threadIdx.x;
    if (bid < 4096) {
        // ---- one (b,s) row: cvt + gate ----
        int lane = tid & 63, wave = tid >> 6;
        const float4* xr = (const float4*)(x + (size_t)bid * 2048);
        float4 p0 = xr[tid * 2], p1 = xr[tid * 2 + 1];
        ((bf16x8*)xb)[bid * 256 + tid] = cvt8(p0, p1);
#pragma unroll
        for (int h = 0; h < 16; ++h) {
            const float4* wr = (const float4*)(wg + (size_t)h * 2048);
            float4 w0 = wr[tid * 2], w1 = wr[tid * 2 + 1];
            float acc = p0.x * w0.x + p0.y * w0.y + p0.z * w0.z + p0.w * w0.w +
                        p1.x * w1.x + p1.y * w1.y + p1.z * w1.z + p1.w * w1.w;
#pragma unroll
            for (int m = 1; m < 64; m <<= 1) acc += __shfl_xor(acc, m);
            if (lane == 0) gp[wave][h] = acc;
        }
        __syncthreads();
        if (tid < 16) {
            int s = bid & 2047, b = bid >> 11;
            float z = gp[0][tid] + gp[1][tid] + gp[2][tid] + gp[3][tid] + bg[tid];
            gate[((size_t)b * 16 + tid) * 2048 + s] = 1.f / (1.f + __expf(-z));
        }
        return;
    }
    if (bid < 7168) {
        cvt_range(wqkv, wqb, (bid - 4096) * 256 + tid);
        return;
    }
    // ---- rope table: idx = s*64 + d0 ----
    int idx = (bid - 7168) * 256 + tid;
    int s = idx >> 6, d0 = idx & 63;
    float freq = (float)s * __expf(-(float)d0 * (9.2103403719761836f / 64.0f));
    ropet[idx] = make_float2(cosf(freq), sinf(freq));
}

// ---------------------------------------------------------------------------
// wo_cvt: w_o fp32 -> bf16 into the Kb/Vtb region (dead after attn).
// ---------------------------------------------------------------------------
__global__ __launch_bounds__(256) void wo_cvt_kernel(const float* __restrict__ wo,
                                                     __bf16* __restrict__ wob) {
    cvt_range(wo, wob, blockIdx.x * 256 + threadIdx.x);
}

// ---------------------------------------------------------------------------
// 8-phase GEMM (m201 template) + T1 XCD swizzle + fused Q/K-normrope
// epilogue (EPI=1, QKV gemm). Round-10 conflict-free fragment swizzle kept.
//   xblk 0-7  (Q tiles): rmsnorm+rope from fp32 accumulators, x SCALE_LOG2E,
//                        written IN PLACE to C (qkv) at the standard tile
//                        location (attn reads Q from there, stride 3072).
//   xblk 8,9  (K tiles): as round 9 — normrope -> Kb, never lands in qkv.
//   xblk 10,11 (V tiles): plain C write (vtrans consumes).
// ldA is a runtime row stride for A (out-GEMM reads qkv with ldA=3072).
// ---------------------------------------------------------------------------
template <int WMT, int WNT, int EPI, typename TC>
__global__ __launch_bounds__(512) void gemm8p(const __bf16* __restrict__ A,
                                              const __bf16* __restrict__ B,
                                              TC* __restrict__ C,
                                              int M, int N, int K, int ldA,
                                              const float* __restrict__ qw,
                                              const float* __restrict__ kw,
                                              const float2* __restrict__ ropet,
                                              __bf16* __restrict__ Kx) {
    constexpr int BM = WMT * 32;   // WARPS_M = 2
    constexpr int BN = WNT * 64;   // WARPS_N = 4
    constexpr int LA = BM / 128;   // gl_lds16 per thread per A half-tile
    constexpr int LB = BN / 128;
    constexpr int VMC = 2 * LA + LB;

    __shared__ __align__(16) __bf16 As[2][BM * 64];
    __shared__ __align__(16) __bf16 Bs[2][BN * 64];

    const int tid = threadIdx.x;
    const int lane = tid & 63, wave = tid >> 6;
    const int wm = wave >> 2, wn = wave & 3;
    const int quad = lane >> 4, mrow = lane & 15;

    // T1 bijective XCD swizzle (nwg % 8 == 0 for both instantiations).
    const int nbx = gridDim.x;
    const int nwg = nbx * gridDim.y;
    const int orig = (int)blockIdx.y * nbx + (int)blockIdx.x;
    const int wg = (orig & 7) * (nwg >> 3) + (orig >> 3);
    const size_t row0 = (size_t)(wg / nbx) * BM;
    const size_t col0 = (size_t)(wg % nbx) * BN;

    // Inverse-swizzled global source offsets for linear gl_lds staging.
    size_t sA[LA], sB[LB];
    int dA[LA], dB[LB];
#pragma unroll
    for (int c = 0; c < LA; ++c) {
        int q = c * 512 + tid;
        int a = q * 16;                       // linear LDS byte offset
        int p = (a >> 4) & 63;                // slot within 1024B subtile
        int rowl = (a >> 11) * 16 + (p >> 2);
        int g = (p & 3) ^ ((p >> 3) & 3);     // logical k-group at this slot
        int col = ((a >> 10) & 1) * 32 + g * 8;
        sA[c] = (size_t)rowl * ldA + col;
        dA[c] = q * 8;
    }
#pragma unroll
    for (int c = 0; c < LB; ++c) {
        int q = c * 512 + tid;
        int a = q * 16;
        int p = (a >> 4) & 63;
        int rowl = (a >> 11) * 16 + (p >> 2);
        int g = (p & 3) ^ ((p >> 3) & 3);
        int col = ((a >> 10) & 1) * 32 + g * 8;
        sB[c] = (size_t)rowl * K + col;
        dB[c] = q * 8;
    }

    const __bf16* Ag = A + row0 * ldA;
    const __bf16* Bg = B + col0 * K;

    f32x4 acc[WMT][WNT];
#pragma unroll
    for (int i = 0; i < WMT; ++i)
#pragma unroll
        for (int j = 0; j < WNT; ++j) acc[i][j] = (f32x4){0.f, 0.f, 0.f, 0.f};

    // Conflict-free per-lane ds_read base (slot = mrow*4 + quad^((mrow>>1)&3)).
    const int abase = mrow * 64 + ((quad ^ ((mrow >> 1) & 3)) * 16);

    bf16x8 af[WMT / 2][2], bf[WNT / 2][2];

#define STA8(buf, h, kt)                                                        \
    _Pragma("unroll") for (int c = 0; c < LA; ++c)                              \
        gl_lds16(Ag + (size_t)(h) * (BM / 2) * ldA + (size_t)(kt) * 64 + sA[c], \
                 &As[buf][(h) * (BM / 2) * 64 + dA[c]])

#define STB8(buf, h, kt)                                                        \
    _Pragma("unroll") for (int c = 0; c < LB; ++c)                              \
        gl_lds16(Bg + (size_t)(h) * (BN / 2) * K + (size_t)(kt) * 64 + sB[c],   \
                 &Bs[buf][(h) * (BN / 2) * 64 + dB[c]])

#define LDA8(buf, mh)                                                           \
    _Pragma("unroll") for (int m2 = 0; m2 < WMT / 2; ++m2)                      \
    _Pragma("unroll") for (int s = 0; s < 2; ++s)                               \
        af[m2][s] = *(const bf16x8*)((const char*)&As[buf][0] +                 \
            ((((mh) * (WMT / 2) + m2) * 2 + wm) * 2 + s) * 1024 + abase)

#define LDB8(buf, nh)                                                           \
    _Pragma("unroll") for (int n2 = 0; n2 < WNT / 2; ++n2)                      \
    _Pragma("unroll") for (int s = 0; s < 2; ++s)                               \
        bf[n2][s] = *(const bf16x8*)((const char*)&Bs[buf][0] +                 \
            ((((nh) * (WNT / 2) + n2) * 4 + wn) * 2 + s) * 1024 + abase)

#define MMA8(mh, nh)                                                            \
    _Pragma("unroll") for (int m2 = 0; m2 < WMT / 2; ++m2)                      \
    _Pragma("unroll") for (int n2 = 0; n2 < WNT / 2; ++n2)                      \
    _Pragma("unroll") for (int s = 0; s < 2; ++s)                               \
        acc[(mh) * (WMT / 2) + m2][(nh) * (WNT / 2) + n2] =                     \
            __builtin_amdgcn_mfma_f32_16x16x32_bf16(                            \
                af[m2][s], bf[n2][s],                                           \
                acc[(mh) * (WMT / 2) + m2][(nh) * (WNT / 2) + n2], 0, 0, 0)

#define BAR8 __builtin_amdgcn_s_barrier()

#define WAITVM                                                                  \
    do {                                                                        \
        if constexpr (VMC == 6)                                                 \
            asm volatile("s_waitcnt vmcnt(6)" ::: "memory");                    \
        else                                                                    \
            asm volatile("s_waitcnt vmcnt(4)" ::: "memory");                    \
    } while (0)

#define PHASE_TAIL(mh, nh)                                                      \
    __builtin_amdgcn_s_barrier();                                               \
    asm volatile("s_waitcnt lgkmcnt(0)" ::: "memory");                          \
    __builtin_amdgcn_sched_barrier(0);                                          \
    __builtin_amdgcn_s_setprio(1);                                              \
    MMA8(mh, nh);                                                               \
    __builtin_amdgcn_s_setprio(0)

    const int NT = K / 64;

    STA8(0, 0, 0);
    STB8(0, 0, 0);
    STA8(0, 1, 0);
    STB8(0, 1, 0);
    STA8(1, 0, 1);
    STB8(1, 1, 1);
    STA8(1, 1, 1);
    WAITVM;
    BAR8;

    for (int i = 0; i < NT / 2; ++i) {
        const int u = 2 * i;
        const int k2 = (u + 2 < NT) ? u + 2 : NT - 1;
        const int k3 = (u + 3 < NT) ? u + 3 : NT - 1;
        // ---- tile u (buf0) ----
        LDA8(0, 0); LDB8(0, 0); STB8(1, 0, u + 1);
        PHASE_TAIL(0, 0); BAR8;
        LDB8(0, 1); STA8(0, 0, k2);
        PHASE_TAIL(0, 1); BAR8;
        LDA8(0, 1); STB8(0, 1, k2);
        PHASE_TAIL(1, 1); BAR8;
        LDB8(0, 0); STA8(0, 1, k2);
        PHASE_TAIL(1, 0); WAITVM; BAR8;
        // ---- tile u+1 (buf1) ----
        LDA8(1, 0); LDB8(1, 0); STB8(0, 0, k2);
        PHASE_TAIL(0, 0); BAR8;
        LDB8(1, 1); STA8(1, 0, k3);
        PHASE_TAIL(0, 1); BAR8;
        LDA8(1, 1); STB8(1, 1, k3);
        PHASE_TAIL(1, 1); BAR8;
        LDB8(1, 0); STA8(1, 1, k3);
        PHASE_TAIL(1, 0); WAITVM; BAR8;
    }
    asm volatile("s_waitcnt vmcnt(0)" ::: "memory");

#undef STA8
#undef STB8
#undef LDA8
#undef LDB8
#undef MMA8
#undef BAR8
#undef WAITVM
#undef PHASE_TAIL

    if constexpr (EPI) {
        int xblk = (int)(col0 >> 8);
        if (xblk < 10) {
            // ---- fused Q/K normrope from fp32 accumulators ----
            // head-local d = (nt&1)*64 + d0, d0 = wn*16+mrow, head pair t=nt>>1.
            __syncthreads();  // LDS quiescent; reuse As for the reduce
            float* sums = (float*)&As[0][0];
            const int d0 = wn * 16 + mrow;
#pragma unroll
            for (int mt = 0; mt < WMT; ++mt)
#pragma unroll
                for (int t = 0; t < 2; ++t) {
                    f32x4 p;
#pragma unroll
                    for (int r = 0; r < 4; ++r)
                        p[r] = acc[mt][2 * t][r] * acc[mt][2 * t][r] +
                               acc[mt][2 * t + 1][r] * acc[mt][2 * t + 1][r];
#pragma unroll
                    for (int m = 1; m < 16; m <<= 1)
#pragma unroll
                        for (int r = 0; r < 4; ++r) p[r] += __shfl_xor(p[r], m);
                    if (mrow == 0) {
                        int idx = ((((wm * 8 + mt) * 4 + quad) * 2 + t) * 4 + wn) * 4;
#pragma unroll
                        for (int r = 0; r < 4; ++r) sums[idx + r] = p[r];
                    }
                }
            __syncthreads();
            const bool isQ = (xblk < 8);
            const float* w = isQ ? qw : kw;
            float w1 = w[d0], w2 = w[d0 + 64];
            float osc = isQ ? SCALE_LOG2E : 1.0f;
#pragma unroll
            for (int mt = 0; mt < WMT; ++mt) {
                int rbase = (int)row0 + (mt * 2 + wm) * 16 + quad * 4;
#pragma unroll
                for (int t = 0; t < 2; ++t) {
                    int ib = (((wm * 8 + mt) * 4 + quad) * 2 + t) * 16;
                    f32x4 sv = *(const f32x4*)&sums[ib] + *(const f32x4*)&sums[ib + 4] +
                               *(const f32x4*)&sums[ib + 8] + *(const f32x4*)&sums[ib + 12];
#pragma unroll
                    for (int r = 0; r < 4; ++r) {
                        int row = rbase + r;
                        int s_ = row & 2047, b_ = row >> 11;
                        float inv = rsqrtf(sv[r] * (1.0f / 128.0f) + 1e-5f);
                        float2 cs = ropet[s_ * 64 + d0];
                        float y1 = acc[mt][2 * t][r] * inv * w1;
                        float y2 = acc[mt][2 * t + 1][r] * inv * w2;
                        float v1 = (y1 * cs.x - y2 * cs.y) * osc;
                        float v2 = (y1 * cs.y + y2 * cs.x) * osc;
                        if (isQ) {
                            // in-place normed Q at the standard tile location
                            size_t base = (size_t)row * N + col0 + (2 * t) * 64 + d0;
                            C[base] = (TC)v1;
                            C[base + 64] = (TC)v2;
                        } else {
                            int kvh = (xblk - 8) * 2 + t;
                            __bf16* dst = Kx + (((size_t)(b_ * 4 + kvh) * 2048 + s_) << 7);
                            dst[d0] = (__bf16)v1;
                            dst[d0 + 64] = (__bf16)v2;
                        }
                    }
                }
            }
            return;  // K never written to qkv; Q written normed in place
        }
    }

#pragma unroll
    for (int mt = 0; mt < WMT; ++mt)
#pragma unroll
        for (int nt = 0; nt < WNT; ++nt)
#pragma unroll
            for (int r = 0; r < 4; ++r) {
                size_t row = row0 + (mt * 2 + wm) * 16 + quad * 4 + r;
                size_t col = col0 + (nt * 4 + wn) * 16 + mrow;
                C[row * N + col] = (TC)fin(acc[mt][nt][r]);
            }
}

// ---------------------------------------------------------------------------
// mid: V transpose only (Q and K normed in the gemm epilogue). 512 blocks.
// ---------------------------------------------------------------------------
__global__ __launch_bounds__(256) void mid_kernel(const __bf16* __restrict__ qkv,
                                                  __bf16* __restrict__ Vt) {
    __shared__ __align__(16) __bf16 tile[64][72];
    int v = blockIdx.x, t = threadIdx.x;
    int st0 = (v & 31) * 64;
    int dblk = (v >> 5) & 1;
    int bz = v >> 6;
    int b = bz >> 2, kv = bz & 3;
    const __bf16* src = qkv + (size_t)(b * 2048 + st0) * 3072 + 2560 + kv * 128 + dblk * 64;
#pragma unroll
    for (int it = 0; it < 2; ++it) {
        int row = it * 32 + (t >> 3);
        int ch = t & 7;
        *(bf16x8*)&tile[row][ch * 8] = *(const bf16x8*)(src + (size_t)row * 3072 + ch * 8);
    }
    __syncthreads();
    __bf16* dst = Vt + ((size_t)(b * 4 + kv) * 128 + dblk * 64) * 2048 + st0;
#pragma unroll
    for (int it = 0; it < 2; ++it) {
        int drow = it * 32 + (t >> 3);
        int sch = t & 7;
        bf16x8 vv;
#pragma unroll
        for (int j = 0; j < 8; ++j) vv[j] = tile[sch * 8 + j][drow];
        *(bf16x8*)(dst + (size_t)drow * 2048 + sch * 8) = vv;
    }
}

// ---------------------------------------------------------------------------
// Flash attention v10 = v9 core (P-swizzle, MFMA-ones row sums, key-split,
// conflict-free merge) with Q read from qkv (stride 3072, normed in the gemm
// epilogue) and O written IN PLACE over the block's own Q region. Safe: each
// block reads its Q once before the first barrier, writes O last, and blocks
// own disjoint (row, head) regions of qkv.
// ---------------------------------------------------------------------------
#define FIXED_M 20.0f

#define MFMA16(a, b, c) __builtin_amdgcn_mfma_f32_16x16x32_bf16(a, b, c, 0, 0, 0)

__device__ __forceinline__ int pswz(int e) { return e ^ (((e >> 7) & 1) << 4); }

template <int MODE>  // 0: both full; 1: h0 diag + h1 full; 2: h1 diag only
__device__ __forceinline__ void attn_step(const __bf16* Kl, const __bf16* Vl,
                                          int ws, int quad, int mrow,
                                          const bf16x8* aq0, const bf16x8* aq1,
                                          f32x4* o0, f32x4* o1,
                                          f32x4& lf0, f32x4& lf1,
                                          __bf16* Pw) {
    bf16x8 ones;
#pragma unroll
    for (int i = 0; i < 8; ++i) ones[i] = (__bf16)1.0f;

    f32x4 sc0[4], sc1[4];
    __builtin_amdgcn_s_setprio(1);
#pragma unroll
    for (int jt = 0; jt < 4; ++jt) {
        f32x4 s0 = (f32x4){0.f, 0.f, 0.f, 0.f};
        f32x4 s1 = (f32x4){0.f, 0.f, 0.f, 0.f};
#pragma unroll
        for (int dt = 0; dt < 4; ++dt) {
            bf16x8 bk = *(const bf16x8*)&Kl[((dt * 4 + quad) * 64 + jt * 16 + mrow) * 8];
            if (MODE < 2) s0 = MFMA16(aq0[dt], bk, s0);
            s1 = MFMA16(aq1[dt], bk, s1);
        }
        sc0[jt] = s0;
        sc1[jt] = s1;
    }
    __builtin_amdgcn_s_setprio(0);

    if (MODE == 1) {
        int rloc = ws * 16 + quad * 4;
#pragma unroll
        for (int jt = 0; jt < 4; ++jt)
#pragma unroll
            for (int r = 0; r < 4; ++r)
                if (jt * 16 + mrow > rloc + r) sc0[jt][r] = -1e30f;
    }
    if (MODE == 2) {
        int rloc = ws * 16 + quad * 4;
#pragma unroll
        for (int jt = 0; jt < 4; ++jt)
#pragma unroll
            for (int r = 0; r < 4; ++r)
                if (jt * 16 + mrow > rloc + r) sc1[jt][r] = -1e30f;
    }

    // Streaming softmax through the SHARED per-wave P buffer (h0 then h1;
    // same-wave DS ops execute in order, so the WAR on Pw is safe).
    const int rb0 = pswz(((0 * 4 + quad) * 16 + mrow) * 8);
    const int rb1 = pswz(((1 * 4 + quad) * 16 + mrow) * 8);
    bf16x8 ap0[2], ap1[2];
    if (MODE < 2) {
#pragma unroll
        for (int jt = 0; jt < 4; ++jt)
#pragma unroll
            for (int r = 0; r < 4; ++r) {
                float pv = exp2f(sc0[jt][r] - FIXED_M);
                int k = jt * 16 + mrow;
                Pw[pswz(((k >> 3) * 16 + quad * 4 + r) * 8 + (k & 7))] = (__bf16)pv;
            }
        ap0[0] = *(const bf16x8*)&Pw[rb0];
        ap0[1] = *(const bf16x8*)&Pw[rb1];
        lf0 = MFMA16(ap0[0], ones, lf0);
        lf0 = MFMA16(ap0[1], ones, lf0);
    }
#pragma unroll
    for (int jt = 0; jt < 4; ++jt)
#pragma unroll
        for (int r = 0; r < 4; ++r) {
            float pv = exp2f(sc1[jt][r] - FIXED_M);
            int k = jt * 16 + mrow;
            Pw[pswz(((k >> 3) * 16 + quad * 4 + r) * 8 + (k & 7))] = (__bf16)pv;
        }
    ap1[0] = *(const bf16x8*)&Pw[rb0];
    ap1[1] = *(const bf16x8*)&Pw[rb1];
    lf1 = MFMA16(ap1[0], ones, lf1);
    lf1 = MFMA16(ap1[1], ones, lf1);

    __builtin_amdgcn_s_setprio(1);
#pragma unroll
    for (int d2 = 0; d2 < 8; ++d2)
#pragma unroll
        for (int ks = 0; ks < 2; ++ks) {
            bf16x8 bv = *(const bf16x8*)&Vl[((ks * 4 + quad) * 128 + d2 * 16 + mrow) * 8];
            if (MODE < 2) o0[d2] = MFMA16(ap0[ks], bv, o0[d2]);
            o1[d2] = MFMA16(ap1[ks], bv, o1[d2]);
        }
    __builtin_amdgcn_s_setprio(0);
}

__global__ __launch_bounds__(512, 2) void attn_kernel(__bf16* __restrict__ qkvO,
                                                      const __bf16* __restrict__ Kx,
                                                      const __bf16* __restrict__ Vt,
                                                      const float* __restrict__ gate) {
    __shared__ __align__(16) __bf16 Kl[2][2][64 * 128];  // [stream][buf]
    __shared__ __align__(16) __bf16 Vl[2][2][128 * 64];  // [stream][buf]
    __shared__ __align__(16) __bf16 Pl[8][1024];
    int tid = threadIdx.x, lane = tid & 63, wave = tid >> 6;

    int ws = wave & 3, st = wave >> 2;  // row-group, stream
    int quad = lane >> 4, mrow = lane & 15;
    __bf16* Pw = &Pl[wave][0];

    int idx = blockIdx.x;
    int qb = 15 - (idx >> 5);  // longest items dispatch first (backfill)
    int h = idx & 15, b = (idx >> 4) & 1;
    int kvh = h >> 2;

    // Staging: threads 0-255 stage the even-stream tile, 256-511 the odd.
    int sst = tid >> 8, lt = tid & 255;
    const __bf16* kbase = Kx + (size_t)(b * 4 + kvh) * 2048 * 128 + (lt & 63) * 128 + (lt >> 6) * 8;
    const __bf16* vbase = Vt + (size_t)(b * 4 + kvh) * 128 * 2048 + (lt & 127) * 2048 + (lt >> 7) * 8;
    int ldst = lt * 8;

    auto STAGE = [&](int buf, int tile) {
        const __bf16* kp = kbase + (size_t)tile * 8192;
        const __bf16* vp = vbase + (size_t)tile * 64;
#pragma unroll
        for (int c = 0; c < 4; ++c) gl_lds16(kp + 32 * c, &Kl[sst][buf][ldst + 2048 * c]);
#pragma unroll
        for (int c = 0; c < 4; ++c) gl_lds16(vp + 16 * c, &Vl[sst][buf][ldst + 2048 * c]);
    };

    STAGE(0, sst);  // even stream: tile 0; odd stream: tile 1

    // Q from qkv (normed+roped in the gemm epilogue), row stride 3072.
    const __bf16* Qh = qkvO + (size_t)(b * 2048 + qb * 128 + ws * 16 + mrow) * 3072 + h * 128;
    bf16x8 aq0[4], aq1[4];
#pragma unroll
    for (int dt = 0; dt < 4; ++dt) {
        aq0[dt] = *(const bf16x8*)(Qh + dt * 32 + quad * 8);
        aq1[dt] = *(const bf16x8*)(Qh + (size_t)64 * 3072 + dt * 32 + quad * 8);
    }

    f32x4 o0[8], o1[8];
#pragma unroll
    for (int d2 = 0; d2 < 8; ++d2) {
        o0[d2] = (f32x4){0.f, 0.f, 0.f, 0.f};
        o1[d2] = (f32x4){0.f, 0.f, 0.f, 0.f};
    }
    f32x4 lf0 = (f32x4){0.f, 0.f, 0.f, 0.f}, lf1 = (f32x4){0.f, 0.f, 0.f, 0.f};

    __syncthreads();  // tiles 0,1 visible (barrier drains gl_lds)

    int cur = 0;
    for (int kt = 0; kt < qb; ++kt) {
        STAGE(cur ^ 1, 2 * (kt + 1) + sst);  // prefetch both streams' next
        attn_step<0>(Kl[st][cur], Vl[st][cur], ws, quad, mrow, aq0, aq1, o0, o1, lf0, lf1, Pw);
        __syncthreads();
        cur ^= 1;
    }
    // Last step: even stream tile 2qb = MODE1; odd stream tile 2qb+1 = MODE2.
    if (st == 0)
        attn_step<1>(Kl[0][cur], Vl[0][cur], ws, quad, mrow, aq0, aq1, o0, o1, lf0, lf1, Pw);
    else
        attn_step<2>(Kl[1][cur], Vl[1][cur], ws, quad, mrow, aq0, aq1, o0, o1, lf0, lf1, Pw);

    // ---- in-block fp32 merge, conflict-free [slot][lane] layout ----
    __syncthreads();  // all waves done with K/V LDS
    f32x4* mo = (f32x4*)&Kl[0][0][0];   // 16 slots x 256 lanes x f32x4 = 64 KB
    float* ml = (float*)&Pl[0][0];      // 8 slots x 256 lanes x f32 = 8 KB
    int mlane = ws * 64 + lane;
    if (st == 1) {
#pragma unroll
        for (int d2 = 0; d2 < 8; ++d2) {
            mo[d2 * 256 + mlane] = o0[d2];
            mo[(d2 + 8) * 256 + mlane] = o1[d2];
        }
#pragma unroll
        for (int r = 0; r < 4; ++r) {
            ml[r * 256 + mlane] = lf0[r];
            ml[(r + 4) * 256 + mlane] = lf1[r];
        }
    }
    __syncthreads();
    if (st == 0) {
#pragma unroll
        for (int d2 = 0; d2 < 8; ++d2) {
            o0[d2] += mo[d2 * 256 + mlane];
            o1[d2] += mo[(d2 + 8) * 256 + mlane];
        }
#pragma unroll
        for (int r = 0; r < 4; ++r) {
            lf0[r] += ml[r * 256 + mlane];
            lf1[r] += ml[(r + 4) * 256 + mlane];
        }
#pragma unroll
        for (int hf = 0; hf < 2; ++hf) {
            f32x4* oo = hf ? o1 : o0;
            f32x4 ll = hf ? lf1 : lf0;
            int srow0 = qb * 128 + hf * 64 + ws * 16 + quad * 4;
            float gv[4], il[4];
#pragma unroll
            for (int r = 0; r < 4; ++r) {
                gv[r] = gate[((size_t)b * 16 + h) * 2048 + srow0 + r];
                il[r] = 1.0f / fmaxf(ll[r], 1e-30f);
            }
            // O in place over this block's own Q region (stride 3072).
#pragma unroll
            for (int d2 = 0; d2 < 8; ++d2)
#pragma unroll
                for (int r = 0; r < 4; ++r)
                    qkvO[(size_t)(b * 2048 + srow0 + r) * 3072 + h * 128 + d2 * 16 + mrow] =
                        (__bf16)fin(oo[d2][r] * il[r] * gv[r]);
        }
    }
}

// ---------------------------------------------------------------------------
// Memory plan (ws <= 33,554,432 B; d_out doubles as scratch where safe).
//   d_out: xb[0,16.7M) + wqb[16.7,29.36M) + gateb[29.36M,+256K) +
//          ropet[29.62M,+1M) -> all dead after attn -> out fp32 [0,33.5M)
//   ws: qkv[0,25.2M): Q-cols normed by gQKV epi, overwritten in place by
//       attn's O (same addresses, per-block self-owned); V-cols dead after
//       mid; K-col range never written. Kb[25.2,29.4M) / Vtb[29.4,33.5M)
//       live through attn, then wob over [25.2,33.5M) (wo_cvt after attn).
// Launch graph (6): prep -> gemmQKV(+Q/K-epi) -> mid(vtrans) -> attn ->
//                   wo_cvt -> gemmOut(A=qkv ldA=3072)
// ---------------------------------------------------------------------------
extern "C" void kernel_launch(void* const* d_in, const int* in_sizes, int n_in,
                              void* d_out, int out_size, void* d_ws, size_t ws_size,
                              hipStream_t stream) {
    const float* x = (const float*)d_in[0];
    const float* w_qkv = (const float*)d_in[1];
    const float* q_norm_w = (const float*)d_in[2];
    const float* k_norm_w = (const float*)d_in[3];
    const float* w_gate = (const float*)d_in[4];
    const float* b_gate = (const float*)d_in[5];
    const float* w_o = (const float*)d_in[6];
    float* out = (float*)d_out;

    char* ws = (char*)d_ws;
    char* od = (char*)d_out;
    __bf16* xb = (__bf16*)(od);
    __bf16* wqb = (__bf16*)(od + 16777216);
    float* gateb = (float*)(od + 29360128);
    float2* ropet = (float2*)(od + 29622272);
    __bf16* qkv = (__bf16*)(ws);
    __bf16* Kb = (__bf16*)(ws + 25165824);
    __bf16* Vtb = (__bf16*)(ws + 29360128);
    __bf16* wob = (__bf16*)(ws + 25165824);  // over Kb+Vtb, dead post-attn

    // prep: cvt x + gate [0,4096) + cvt w_qkv [4096,7168) + rope table [7168,7680)
    prep_kernel<<<7680, 256, 0, stream>>>(x, w_qkv, xb, wqb, w_gate, b_gate, gateb, ropet);
    // QKV GEMM: 256x256 tile, 12x16 = 192 blocks; Q normed in place, K -> Kb.
    gemm8p<8, 4, 1, __bf16><<<dim3(3072 / 256, 4096 / 256), 512, 0, stream>>>(
        xb, wqb, qkv, 4096, 3072, 2048, 2048, q_norm_w, k_norm_w, ropet, Kb);
    // mid: vtrans only (512 blocks)
    mid_kernel<<<512, 256, 0, stream>>>(qkv, Vtb);
    // attn: Q from qkv, O in place over Q
    attn_kernel<<<512, 512, 0, stream>>>(qkv, Kb, Vtb, gateb);
    // w_o cvt into the dead Kb/Vtb region
    wo_cvt_kernel<<<2048, 256, 0, stream>>>(w_o, wob);
    // Output GEMM: 128x256 tile, 8x32 = 256 blocks; A = qkv with ldA=3072.
    gemm8p<4, 4, 0, float><<<dim3(2048 / 256, 4096 / 128), 512, 0, stream>>>(
        qkv, wob, out, 4096, 2048, 2048, 3072, nullptr, nullptr, nullptr, nullptr);
}

// Round 14
// 342.258 us; speedup vs baseline: 1.0387x; 1.0387x over previous
//
#include <hip/hip_runtime.h>

typedef __bf16 bf16x8 __attribute__((ext_vector_type(8)));
typedef float f32x4 __attribute__((ext_vector_type(4)));

typedef __attribute__((address_space(1))) void gvoid;
typedef __attribute__((address_space(3))) void lvoid;

__device__ __forceinline__ void gl_lds16(const void* g, void* l) {
    __builtin_amdgcn_global_load_lds((gvoid*)g, (lvoid*)l, 16, 0, 0);
}

// NaN/inf scrub for epilogues only.
__device__ __forceinline__ float fin(float v) {
    v = (v == v) ? v : 0.f;
    return fminf(fmaxf(v, -3.0e38f), 3.0e38f);
}

__device__ __forceinline__ bf16x8 cvt8(float4 a, float4 b) {
    bf16x8 r;
    r[0] = (__bf16)a.x; r[1] = (__bf16)a.y; r[2] = (__bf16)a.z; r[3] = (__bf16)a.w;
    r[4] = (__bf16)b.x; r[5] = (__bf16)b.y; r[6] = (__bf16)b.z; r[7] = (__bf16)b.w;
    return r;
}

__device__ __forceinline__ void cvt_range(const float* __restrict__ in,
                                          __bf16* __restrict__ out, int i) {
    const float4* p = (const float4*)in + (size_t)i * 2;
    ((bf16x8*)out)[i] = cvt8(p[0], p[1]);
}

#define SCALE_LOG2E 0.12751666797152713f

// ---------------------------------------------------------------------------
// prep: fused cvt(x)+gate, cvt(w_qkv), rope table. (unchanged from round 8)
// ---------------------------------------------------------------------------
__global__ __launch_bounds__(256) void prep_kernel(const float* __restrict__ x,
                                                   const float* __restrict__ wqkv,
                                                   __bf16* __restrict__ xb,
                                                   __bf16* __restrict__ wqb,
                                                   const float* __restrict__ wg,
                                                   const float* __restrict__ bg,
                                                   float* __restrict__ gate,
                                                   float2* __restrict__ ropet) {
    __shared__ float gp[4][16];
    int bid = blockIdx.x, tid = threadIdx.x;
    if (bid < 4096) {
        // ---- one (b,s) row: cvt + gate ----
        int lane = tid & 63, wave = tid >> 6;
        const float4* xr = (const float4*)(x + (size_t)bid * 2048);
        float4 p0 = xr[tid * 2], p1 = xr[tid * 2 + 1];
        ((bf16x8*)xb)[bid * 256 + tid] = cvt8(p0, p1);
#pragma unroll
        for (int h = 0; h < 16; ++h) {
            const float4* wr = (const float4*)(wg + (size_t)h * 2048);
            float4 w0 = wr[tid * 2], w1 = wr[tid * 2 + 1];
            float acc = p0.x * w0.x + p0.y * w0.y + p0.z * w0.z + p0.w * w0.w +
                        p1.x * w1.x + p1.y * w1.y + p1.z * w1.z + p1.w * w1.w;
#pragma unroll
            for (int m = 1; m < 64; m <<= 1) acc += __shfl_xor(acc, m);
            if (lane == 0) gp[wave][h] = acc;
        }
        __syncthreads();
        if (tid < 16) {
            int s = bid & 2047, b = bid >> 11;
            float z = gp[0][tid] + gp[1][tid] + gp[2][tid] + gp[3][tid] + bg[tid];
            gate[((size_t)b * 16 + tid) * 2048 + s] = 1.f / (1.f + __expf(-z));
        }
        return;
    }
    if (bid < 7168) {
        cvt_range(wqkv, wqb, (bid - 4096) * 256 + tid);
        return;
    }
    // ---- rope table: idx = s*64 + d0 ----
    int idx = (bid - 7168) * 256 + tid;
    int s = idx >> 6, d0 = idx & 63;
    float freq = (float)s * __expf(-(float)d0 * (9.2103403719761836f / 64.0f));
    ropet[idx] = make_float2(cosf(freq), sinf(freq));
}

// ---------------------------------------------------------------------------
// wo_cvt: w_o fp32 -> bf16 into the Kb/Vtb region (dead after attn).
// ---------------------------------------------------------------------------
__global__ __launch_bounds__(256) void wo_cvt_kernel(const float* __restrict__ wo,
                                                     __bf16* __restrict__ wob) {
    cvt_range(wo, wob, blockIdx.x * 256 + threadIdx.x);
}

// ---------------------------------------------------------------------------
// 8-phase GEMM, ROUND-13: 128x128 tiles (WMT=4, WNT=2) -> LDS 64 KiB ->
// 2 blocks/CU co-resident (the m97 mechanism: one block's MFMA hides the
// other's barrier/vmcnt drains — at 256x256 the kernel measured 75% idle
// with MfmaUtil 16% and nothing else busy). Full grids (768 / 512 blocks).
// Counted vmcnt is config-exact: VMC = stages issued in P2..P4 = 2*LA+LB
// (vmcnt(3) here; the old fixed else-branch vmcnt(4) would leave P1's
// stage outstanding when P5 reads it). r10 fragment swizzle retained
// (bank-balanced; note: r1's was also balanced — conflicts were never the
// gemm bottleneck, SQ_LDS_BANK_CONFLICT=0 in all runs).
// Epilogue (EPI=1): BN=128 = exactly one head. xblk = col0/128:
//   0-15  Q head h=xblk: fp32 rmsnorm+rope (x SCALE_LOG2E), in place to C.
//   16-19 K kvh=xblk-16: fp32 rmsnorm+rope -> Kx. 20-23 V: plain write.
// ---------------------------------------------------------------------------
template <int WMT, int WNT, int EPI, typename TC>
__global__ __launch_bounds__(512, 4) void gemm8p(const __bf16* __restrict__ A,
                                                 const __bf16* __restrict__ B,
                                                 TC* __restrict__ C,
                                                 int M, int N, int K, int ldA,
                                                 const float* __restrict__ qw,
                                                 const float* __restrict__ kw,
                                                 const float2* __restrict__ ropet,
                                                 __bf16* __restrict__ Kx) {
    constexpr int BM = WMT * 32;   // WARPS_M = 2
    constexpr int BN = WNT * 64;   // WARPS_N = 4
    constexpr int LA = BM / 128;   // gl_lds16 per thread per A half-tile
    constexpr int LB = BN / 128;
    constexpr int VMC = 2 * LA + LB;

    __shared__ __align__(16) __bf16 As[2][BM * 64];
    __shared__ __align__(16) __bf16 Bs[2][BN * 64];

    const int tid = threadIdx.x;
    const int lane = tid & 63, wave = tid >> 6;
    const int wm = wave >> 2, wn = wave & 3;
    const int quad = lane >> 4, mrow = lane & 15;

    // T1 bijective XCD swizzle (nwg % 8 == 0 for both instantiations).
    const int nbx = gridDim.x;
    const int nwg = nbx * gridDim.y;
    const int orig = (int)blockIdx.y * nbx + (int)blockIdx.x;
    const int wg = (orig & 7) * (nwg >> 3) + (orig >> 3);
    const size_t row0 = (size_t)(wg / nbx) * BM;
    const size_t col0 = (size_t)(wg % nbx) * BN;

    // Inverse-swizzled global source offsets for linear gl_lds staging.
    size_t sA[LA], sB[LB];
    int dA[LA], dB[LB];
#pragma unroll
    for (int c = 0; c < LA; ++c) {
        int q = c * 512 + tid;
        int a = q * 16;                       // linear LDS byte offset
        int p = (a >> 4) & 63;                // slot within 1024B subtile
        int rowl = (a >> 11) * 16 + (p >> 2);
        int g = (p & 3) ^ ((p >> 3) & 3);     // logical k-group at this slot
        int col = ((a >> 10) & 1) * 32 + g * 8;
        sA[c] = (size_t)rowl * ldA + col;
        dA[c] = q * 8;
    }
#pragma unroll
    for (int c = 0; c < LB; ++c) {
        int q = c * 512 + tid;
        int a = q * 16;
        int p = (a >> 4) & 63;
        int rowl = (a >> 11) * 16 + (p >> 2);
        int g = (p & 3) ^ ((p >> 3) & 3);
        int col = ((a >> 10) & 1) * 32 + g * 8;
        sB[c] = (size_t)rowl * K + col;
        dB[c] = q * 8;
    }

    const __bf16* Ag = A + row0 * ldA;
    const __bf16* Bg = B + col0 * K;

    f32x4 acc[WMT][WNT];
#pragma unroll
    for (int i = 0; i < WMT; ++i)
#pragma unroll
        for (int j = 0; j < WNT; ++j) acc[i][j] = (f32x4){0.f, 0.f, 0.f, 0.f};

    // Bank-balanced per-lane ds_read base (slot = mrow*4 + quad^((mrow>>1)&3)).
    const int abase = mrow * 64 + ((quad ^ ((mrow >> 1) & 3)) * 16);

    bf16x8 af[WMT / 2][2], bf[WNT / 2][2];

#define STA8(buf, h, kt)                                                        \
    _Pragma("unroll") for (int c = 0; c < LA; ++c)                              \
        gl_lds16(Ag + (size_t)(h) * (BM / 2) * ldA + (size_t)(kt) * 64 + sA[c], \
                 &As[buf][(h) * (BM / 2) * 64 + dA[c]])

#define STB8(buf, h, kt)                                                        \
    _Pragma("unroll") for (int c = 0; c < LB; ++c)                              \
        gl_lds16(Bg + (size_t)(h) * (BN / 2) * K + (size_t)(kt) * 64 + sB[c],   \
                 &Bs[buf][(h) * (BN / 2) * 64 + dB[c]])

#define LDA8(buf, mh)                                                           \
    _Pragma("unroll") for (int m2 = 0; m2 < WMT / 2; ++m2)                      \
    _Pragma("unroll") for (int s = 0; s < 2; ++s)                               \
        af[m2][s] = *(const bf16x8*)((const char*)&As[buf][0] +                 \
            ((((mh) * (WMT / 2) + m2) * 2 + wm) * 2 + s) * 1024 + abase)

#define LDB8(buf, nh)                                                           \
    _Pragma("unroll") for (int n2 = 0; n2 < WNT / 2; ++n2)                      \
    _Pragma("unroll") for (int s = 0; s < 2; ++s)                               \
        bf[n2][s] = *(const bf16x8*)((const char*)&Bs[buf][0] +                 \
            ((((nh) * (WNT / 2) + n2) * 4 + wn) * 2 + s) * 1024 + abase)

#define MMA8(mh, nh)                                                            \
    _Pragma("unroll") for (int m2 = 0; m2 < WMT / 2; ++m2)                      \
    _Pragma("unroll") for (int n2 = 0; n2 < WNT / 2; ++n2)                      \
    _Pragma("unroll") for (int s = 0; s < 2; ++s)                               \
        acc[(mh) * (WMT / 2) + m2][(nh) * (WNT / 2) + n2] =                     \
            __builtin_amdgcn_mfma_f32_16x16x32_bf16(                            \
                af[m2][s], bf[n2][s],                                           \
                acc[(mh) * (WMT / 2) + m2][(nh) * (WNT / 2) + n2], 0, 0, 0)

#define BAR8 __builtin_amdgcn_s_barrier()

#define WAITVM                                                                  \
    do {                                                                        \
        if constexpr (VMC == 6)                                                 \
            asm volatile("s_waitcnt vmcnt(6)" ::: "memory");                    \
        else if constexpr (VMC == 4)                                            \
            asm volatile("s_waitcnt vmcnt(4)" ::: "memory");                    \
        else                                                                    \
            asm volatile("s_waitcnt vmcnt(3)" ::: "memory");                    \
    } while (0)

#define PHASE_TAIL(mh, nh)                                                      \
    __builtin_amdgcn_s_barrier();                                               \
    asm volatile("s_waitcnt lgkmcnt(0)" ::: "memory");                          \
    __builtin_amdgcn_sched_barrier(0);                                          \
    __builtin_amdgcn_s_setprio(1);                                              \
    MMA8(mh, nh);                                                               \
    __builtin_amdgcn_s_setprio(0)

    const int NT = K / 64;

    STA8(0, 0, 0);
    STB8(0, 0, 0);
    STA8(0, 1, 0);
    STB8(0, 1, 0);
    STA8(1, 0, 1);
    STB8(1, 1, 1);
    STA8(1, 1, 1);
    WAITVM;
    BAR8;

    for (int i = 0; i < NT / 2; ++i) {
        const int u = 2 * i;
        const int k2 = (u + 2 < NT) ? u + 2 : NT - 1;
        const int k3 = (u + 3 < NT) ? u + 3 : NT - 1;
        // ---- tile u (buf0) ----
        LDA8(0, 0); LDB8(0, 0); STB8(1, 0, u + 1);
        PHASE_TAIL(0, 0); BAR8;
        LDB8(0, 1); STA8(0, 0, k2);
        PHASE_TAIL(0, 1); BAR8;
        LDA8(0, 1); STB8(0, 1, k2);
        PHASE_TAIL(1, 1); BAR8;
        LDB8(0, 0); STA8(0, 1, k2);
        PHASE_TAIL(1, 0); WAITVM; BAR8;
        // ---- tile u+1 (buf1) ----
        LDA8(1, 0); LDB8(1, 0); STB8(0, 0, k2);
        PHASE_TAIL(0, 0); BAR8;
        LDB8(1, 1); STA8(1, 0, k3);
        PHASE_TAIL(0, 1); BAR8;
        LDA8(1, 1); STB8(1, 1, k3);
        PHASE_TAIL(1, 1); BAR8;
        LDB8(1, 0); STA8(1, 1, k3);
        PHASE_TAIL(1, 0); WAITVM; BAR8;
    }
    asm volatile("s_waitcnt vmcnt(0)" ::: "memory");

#undef STA8
#undef STB8
#undef LDA8
#undef LDB8
#undef MMA8
#undef BAR8
#undef WAITVM
#undef PHASE_TAIL

    if constexpr (EPI) {
        int xblk = (int)(col0 >> 7);  // BN=128: one head per tile
        if (xblk < 20) {
            // ---- fused Q/K normrope from fp32 accumulators ----
            // d = nt*64 + d0, d0 = wn*16+mrow; acc[mt][0]/acc[mt][1] are the
            // rope pair (d, d+64).
            __syncthreads();  // LDS quiescent; reuse As for the reduce
            float* sums = (float*)&As[0][0];  // [wm][mt][quad][wn][r] = 512 f32
            const int d0 = wn * 16 + mrow;
#pragma unroll
            for (int mt = 0; mt < WMT; ++mt) {
                f32x4 p;
#pragma unroll
                for (int r = 0; r < 4; ++r)
                    p[r] = acc[mt][0][r] * acc[mt][0][r] +
                           acc[mt][1][r] * acc[mt][1][r];
#pragma unroll
                for (int m = 1; m < 16; m <<= 1)
#pragma unroll
                    for (int r = 0; r < 4; ++r) p[r] += __shfl_xor(p[r], m);
                if (mrow == 0) {
                    int idx = (((wm * 4 + mt) * 4 + quad) * 4 + wn) * 4;
#pragma unroll
                    for (int r = 0; r < 4; ++r) sums[idx + r] = p[r];
                }
            }
            __syncthreads();
            const bool isQ = (xblk < 16);
            const float* w = isQ ? qw : kw;
            float w1 = w[d0], w2 = w[d0 + 64];
            float osc = isQ ? SCALE_LOG2E : 1.0f;
            int kvh = xblk - 16;
#pragma unroll
            for (int mt = 0; mt < WMT; ++mt) {
                int rbase = (int)row0 + (mt * 2 + wm) * 16 + quad * 4;
                int ib = ((wm * 4 + mt) * 4 + quad) * 16;
                f32x4 sv = *(const f32x4*)&sums[ib] + *(const f32x4*)&sums[ib + 4] +
                           *(const f32x4*)&sums[ib + 8] + *(const f32x4*)&sums[ib + 12];
#pragma unroll
                for (int r = 0; r < 4; ++r) {
                    int row = rbase + r;
                    int s_ = row & 2047, b_ = row >> 11;
                    float inv = rsqrtf(sv[r] * (1.0f / 128.0f) + 1e-5f);
                    float2 cs = ropet[s_ * 64 + d0];
                    float y1 = acc[mt][0][r] * inv * w1;
                    float y2 = acc[mt][1][r] * inv * w2;
                    float v1 = (y1 * cs.x - y2 * cs.y) * osc;
                    float v2 = (y1 * cs.y + y2 * cs.x) * osc;
                    if (isQ) {
                        size_t base = (size_t)row * N + col0 + d0;
                        C[base] = (TC)v1;
                        C[base + 64] = (TC)v2;
                    } else {
                        __bf16* dst = Kx + (((size_t)(b_ * 4 + kvh) * 2048 + s_) << 7);
                        dst[d0] = (__bf16)v1;
                        dst[d0 + 64] = (__bf16)v2;
                    }
                }
            }
            return;  // K never written to qkv; Q written normed in place
        }
    }

#pragma unroll
    for (int mt = 0; mt < WMT; ++mt)
#pragma unroll
        for (int nt = 0; nt < WNT; ++nt)
#pragma unroll
            for (int r = 0; r < 4; ++r) {
                size_t row = row0 + (mt * 2 + wm) * 16 + quad * 4 + r;
                size_t col = col0 + (nt * 4 + wn) * 16 + mrow;
                C[row * N + col] = (TC)fin(acc[mt][nt][r]);
            }
}

// ---------------------------------------------------------------------------
// mid: V transpose only (Q and K normed in the gemm epilogue). 512 blocks.
// ---------------------------------------------------------------------------
__global__ __launch_bounds__(256) void mid_kernel(const __bf16* __restrict__ qkv,
                                                  __bf16* __restrict__ Vt) {
    __shared__ __align__(16) __bf16 tile[64][72];
    int v = blockIdx.x, t = threadIdx.x;
    int st0 = (v & 31) * 64;
    int dblk = (v >> 5) & 1;
    int bz = v >> 6;
    int b = bz >> 2, kv = bz & 3;
    const __bf16* src = qkv + (size_t)(b * 2048 + st0) * 3072 + 2560 + kv * 128 + dblk * 64;
#pragma unroll
    for (int it = 0; it < 2; ++it) {
        int row = it * 32 + (t >> 3);
        int ch = t & 7;
        *(bf16x8*)&tile[row][ch * 8] = *(const bf16x8*)(src + (size_t)row * 3072 + ch * 8);
    }
    __syncthreads();
    __bf16* dst = Vt + ((size_t)(b * 4 + kv) * 128 + dblk * 64) * 2048 + st0;
#pragma unroll
    for (int it = 0; it < 2; ++it) {
        int drow = it * 32 + (t >> 3);
        int sch = t & 7;
        bf16x8 vv;
#pragma unroll
        for (int j = 0; j < 8; ++j) vv[j] = tile[sch * 8 + j][drow];
        *(bf16x8*)(dst + (size_t)drow * 2048 + sch * 8) = vv;
    }
}

// ---------------------------------------------------------------------------
// Flash attention v10 (unchanged from round 12): P-swizzle, MFMA-ones row
// sums, key-split-in-block, conflict-free merge; Q from qkv (stride 3072),
// O written in place over the block's own Q region.
// ---------------------------------------------------------------------------
#define FIXED_M 20.0f

#define MFMA16(a, b, c) __builtin_amdgcn_mfma_f32_16x16x32_bf16(a, b, c, 0, 0, 0)

__device__ __forceinline__ int pswz(int e) { return e ^ (((e >> 7) & 1) << 4); }

template <int MODE>  // 0: both full; 1: h0 diag + h1 full; 2: h1 diag only
__device__ __forceinline__ void attn_step(const __bf16* Kl, const __bf16* Vl,
                                          int ws, int quad, int mrow,
                                          const bf16x8* aq0, const bf16x8* aq1,
                                          f32x4* o0, f32x4* o1,
                                          f32x4& lf0, f32x4& lf1,
                                          __bf16* Pw) {
    bf16x8 ones;
#pragma unroll
    for (int i = 0; i < 8; ++i) ones[i] = (__bf16)1.0f;

    f32x4 sc0[4], sc1[4];
    __builtin_amdgcn_s_setprio(1);
#pragma unroll
    for (int jt = 0; jt < 4; ++jt) {
        f32x4 s0 = (f32x4){0.f, 0.f, 0.f, 0.f};
        f32x4 s1 = (f32x4){0.f, 0.f, 0.f, 0.f};
#pragma unroll
        for (int dt = 0; dt < 4; ++dt) {
            bf16x8 bk = *(const bf16x8*)&Kl[((dt * 4 + quad) * 64 + jt * 16 + mrow) * 8];
            if (MODE < 2) s0 = MFMA16(aq0[dt], bk, s0);
            s1 = MFMA16(aq1[dt], bk, s1);
        }
        sc0[jt] = s0;
        sc1[jt] = s1;
    }
    __builtin_amdgcn_s_setprio(0);

    if (MODE == 1) {
        int rloc = ws * 16 + quad * 4;
#pragma unroll
        for (int jt = 0; jt < 4; ++jt)
#pragma unroll
            for (int r = 0; r < 4; ++r)
                if (jt * 16 + mrow > rloc + r) sc0[jt][r] = -1e30f;
    }
    if (MODE == 2) {
        int rloc = ws * 16 + quad * 4;
#pragma unroll
        for (int jt = 0; jt < 4; ++jt)
#pragma unroll
            for (int r = 0; r < 4; ++r)
                if (jt * 16 + mrow > rloc + r) sc1[jt][r] = -1e30f;
    }

    // Streaming softmax through the SHARED per-wave P buffer (h0 then h1;
    // same-wave DS ops execute in order, so the WAR on Pw is safe).
    const int rb0 = pswz(((0 * 4 + quad) * 16 + mrow) * 8);
    const int rb1 = pswz(((1 * 4 + quad) * 16 + mrow) * 8);
    bf16x8 ap0[2], ap1[2];
    if (MODE < 2) {
#pragma unroll
        for (int jt = 0; jt < 4; ++jt)
#pragma unroll
            for (int r = 0; r < 4; ++r) {
                float pv = exp2f(sc0[jt][r] - FIXED_M);
                int k = jt * 16 + mrow;
                Pw[pswz(((k >> 3) * 16 + quad * 4 + r) * 8 + (k & 7))] = (__bf16)pv;
            }
        ap0[0] = *(const bf16x8*)&Pw[rb0];
        ap0[1] = *(const bf16x8*)&Pw[rb1];
        lf0 = MFMA16(ap0[0], ones, lf0);
        lf0 = MFMA16(ap0[1], ones, lf0);
    }
#pragma unroll
    for (int jt = 0; jt < 4; ++jt)
#pragma unroll
        for (int r = 0; r < 4; ++r) {
            float pv = exp2f(sc1[jt][r] - FIXED_M);
            int k = jt * 16 + mrow;
            Pw[pswz(((k >> 3) * 16 + quad * 4 + r) * 8 + (k & 7))] = (__bf16)pv;
        }
    ap1[0] = *(const bf16x8*)&Pw[rb0];
    ap1[1] = *(const bf16x8*)&Pw[rb1];
    lf1 = MFMA16(ap1[0], ones, lf1);
    lf1 = MFMA16(ap1[1], ones, lf1);

    __builtin_amdgcn_s_setprio(1);
#pragma unroll
    for (int d2 = 0; d2 < 8; ++d2)
#pragma unroll
        for (int ks = 0; ks < 2; ++ks) {
            bf16x8 bv = *(const bf16x8*)&Vl[((ks * 4 + quad) * 128 + d2 * 16 + mrow) * 8];
            if (MODE < 2) o0[d2] = MFMA16(ap0[ks], bv, o0[d2]);
            o1[d2] = MFMA16(ap1[ks], bv, o1[d2]);
        }
    __builtin_amdgcn_s_setprio(0);
}

__global__ __launch_bounds__(512, 2) void attn_kernel(__bf16* __restrict__ qkvO,
                                                      const __bf16* __restrict__ Kx,
                                                      const __bf16* __restrict__ Vt,
                                                      const float* __restrict__ gate) {
    __shared__ __align__(16) __bf16 Kl[2][2][64 * 128];  // [stream][buf]
    __shared__ __align__(16) __bf16 Vl[2][2][128 * 64];  // [stream][buf]
    __shared__ __align__(16) __bf16 Pl[8][1024];
    int tid = threadIdx.x, lane = tid & 63, wave = tid >> 6;

    int ws = wave & 3, st = wave >> 2;  // row-group, stream
    int quad = lane >> 4, mrow = lane & 15;
    __bf16* Pw = &Pl[wave][0];

    int idx = blockIdx.x;
    int qb = 15 - (idx >> 5);  // longest items dispatch first (backfill)
    int h = idx & 15, b = (idx >> 4) & 1;
    int kvh = h >> 2;

    // Staging: threads 0-255 stage the even-stream tile, 256-511 the odd.
    int sst = tid >> 8, lt = tid & 255;
    const __bf16* kbase = Kx + (size_t)(b * 4 + kvh) * 2048 * 128 + (lt & 63) * 128 + (lt >> 6) * 8;
    const __bf16* vbase = Vt + (size_t)(b * 4 + kvh) * 128 * 2048 + (lt & 127) * 2048 + (lt >> 7) * 8;
    int ldst = lt * 8;

    auto STAGE = [&](int buf, int tile) {
        const __bf16* kp = kbase + (size_t)tile * 8192;
        const __bf16* vp = vbase + (size_t)tile * 64;
#pragma unroll
        for (int c = 0; c < 4; ++c) gl_lds16(kp + 32 * c, &Kl[sst][buf][ldst + 2048 * c]);
#pragma unroll
        for (int c = 0; c < 4; ++c) gl_lds16(vp + 16 * c, &Vl[sst][buf][ldst + 2048 * c]);
    };

    STAGE(0, sst);  // even stream: tile 0; odd stream: tile 1

    // Q from qkv (normed+roped in the gemm epilogue), row stride 3072.
    const __bf16* Qh = qkvO + (size_t)(b * 2048 + qb * 128 + ws * 16 + mrow) * 3072 + h * 128;
    bf16x8 aq0[4], aq1[4];
#pragma unroll
    for (int dt = 0; dt < 4; ++dt) {
        aq0[dt] = *(const bf16x8*)(Qh + dt * 32 + quad * 8);
        aq1[dt] = *(const bf16x8*)(Qh + (size_t)64 * 3072 + dt * 32 + quad * 8);
    }

    f32x4 o0[8], o1[8];
#pragma unroll
    for (int d2 = 0; d2 < 8; ++d2) {
        o0[d2] = (f32x4){0.f, 0.f, 0.f, 0.f};
        o1[d2] = (f32x4){0.f, 0.f, 0.f, 0.f};
    }
    f32x4 lf0 = (f32x4){0.f, 0.f, 0.f, 0.f}, lf1 = (f32x4){0.f, 0.f, 0.f, 0.f};

    __syncthreads();  // tiles 0,1 visible (barrier drains gl_lds)

    int cur = 0;
    for (int kt = 0; kt < qb; ++kt) {
        STAGE(cur ^ 1, 2 * (kt + 1) + sst);  // prefetch both streams' next
        attn_step<0>(Kl[st][cur], Vl[st][cur], ws, quad, mrow, aq0, aq1, o0, o1, lf0, lf1, Pw);
        __syncthreads();
        cur ^= 1;
    }
    // Last step: even stream tile 2qb = MODE1; odd stream tile 2qb+1 = MODE2.
    if (st == 0)
        attn_step<1>(Kl[0][cur], Vl[0][cur], ws, quad, mrow, aq0, aq1, o0, o1, lf0, lf1, Pw);
    else
        attn_step<2>(Kl[1][cur], Vl[1][cur], ws, quad, mrow, aq0, aq1, o0, o1, lf0, lf1, Pw);

    // ---- in-block fp32 merge, conflict-free [slot][lane] layout ----
    __syncthreads();  // all waves done with K/V LDS
    f32x4* mo = (f32x4*)&Kl[0][0][0];   // 16 slots x 256 lanes x f32x4 = 64 KB
    float* ml = (float*)&Pl[0][0];      // 8 slots x 256 lanes x f32 = 8 KB
    int mlane = ws * 64 + lane;
    if (st == 1) {
#pragma unroll
        for (int d2 = 0; d2 < 8; ++d2) {
            mo[d2 * 256 + mlane] = o0[d2];
            mo[(d2 + 8) * 256 + mlane] = o1[d2];
        }
#pragma unroll
        for (int r = 0; r < 4; ++r) {
            ml[r * 256 + mlane] = lf0[r];
            ml[(r + 4) * 256 + mlane] = lf1[r];
        }
    }
    __syncthreads();
    if (st == 0) {
#pragma unroll
        for (int d2 = 0; d2 < 8; ++d2) {
            o0[d2] += mo[d2 * 256 + mlane];
            o1[d2] += mo[(d2 + 8) * 256 + mlane];
        }
#pragma unroll
        for (int r = 0; r < 4; ++r) {
            lf0[r] += ml[r * 256 + mlane];
            lf1[r] += ml[(r + 4) * 256 + mlane];
        }
#pragma unroll
        for (int hf = 0; hf < 2; ++hf) {
            f32x4* oo = hf ? o1 : o0;
            f32x4 ll = hf ? lf1 : lf0;
            int srow0 = qb * 128 + hf * 64 + ws * 16 + quad * 4;
            float gv[4], il[4];
#pragma unroll
            for (int r = 0; r < 4; ++r) {
                gv[r] = gate[((size_t)b * 16 + h) * 2048 + srow0 + r];
                il[r] = 1.0f / fmaxf(ll[r], 1e-30f);
            }
            // O in place over this block's own Q region (stride 3072).
#pragma unroll
            for (int d2 = 0; d2 < 8; ++d2)
#pragma unroll
                for (int r = 0; r < 4; ++r)
                    qkvO[(size_t)(b * 2048 + srow0 + r) * 3072 + h * 128 + d2 * 16 + mrow] =
                        (__bf16)fin(oo[d2][r] * il[r] * gv[r]);
        }
    }
}

// ---------------------------------------------------------------------------
// Memory plan (ws <= 33,554,432 B; d_out doubles as scratch where safe).
//   d_out: xb[0,16.7M) + wqb[16.7,29.36M) + gateb[29.36M,+256K) +
//          ropet[29.62M,+1M) -> all dead after attn -> out fp32 [0,33.5M)
//   ws: qkv[0,25.2M): Q-cols normed by gQKV epi, overwritten in place by
//       attn's O; V-cols dead after mid; K-col range never written.
//       Kb[25.2,29.4M) / Vtb[29.4,33.5M) live through attn, then wob over
//       [25.2,33.5M) (wo_cvt after attn).
// Launch graph (6): prep -> gemmQKV(+Q/K-epi) -> mid(vtrans) -> attn ->
//                   wo_cvt -> gemmOut(A=qkv ldA=3072)
// ---------------------------------------------------------------------------
extern "C" void kernel_launch(void* const* d_in, const int* in_sizes, int n_in,
                              void* d_out, int out_size, void* d_ws, size_t ws_size,
                              hipStream_t stream) {
    const float* x = (const float*)d_in[0];
    const float* w_qkv = (const float*)d_in[1];
    const float* q_norm_w = (const float*)d_in[2];
    const float* k_norm_w = (const float*)d_in[3];
    const float* w_gate = (const float*)d_in[4];
    const float* b_gate = (const float*)d_in[5];
    const float* w_o = (const float*)d_in[6];
    float* out = (float*)d_out;

    char* ws = (char*)d_ws;
    char* od = (char*)d_out;
    __bf16* xb = (__bf16*)(od);
    __bf16* wqb = (__bf16*)(od + 16777216);
    float* gateb = (float*)(od + 29360128);
    float2* ropet = (float2*)(od + 29622272);
    __bf16* qkv = (__bf16*)(ws);
    __bf16* Kb = (__bf16*)(ws + 25165824);
    __bf16* Vtb = (__bf16*)(ws + 29360128);
    __bf16* wob = (__bf16*)(ws + 25165824);  // over Kb+Vtb, dead post-attn

    // prep: cvt x + gate [0,4096) + cvt w_qkv [4096,7168) + rope table [7168,7680)
    prep_kernel<<<7680, 256, 0, stream>>>(x, w_qkv, xb, wqb, w_gate, b_gate, gateb, ropet);
    // QKV GEMM: 128x128 tile, grid 24x32 = 768 blocks (2 blocks/CU).
    gemm8p<4, 2, 1, __bf16><<<dim3(3072 / 128, 4096 / 128), 512, 0, stream>>>(
        xb, wqb, qkv, 4096, 3072, 2048, 2048, q_norm_w, k_norm_w, ropet, Kb);
    // mid: vtrans only (512 blocks)
    mid_kernel<<<512, 256, 0, stream>>>(qkv, Vtb);
    // attn: Q from qkv, O in place over Q
    attn_kernel<<<512, 512, 0, stream>>>(qkv, Kb, Vtb, gateb);
    // w_o cvt into the dead Kb/Vtb region
    wo_cvt_kernel<<<2048, 256, 0, stream>>>(w_o, wob);
    // Output GEMM: 128x128 tile, grid 16x32 = 512 blocks; A = qkv ldA=3072.
    gemm8p<4, 2, 0, float><<<dim3(2048 / 128, 4096 / 128), 512, 0, stream>>>(
        qkv, wob, out, 4096, 2048, 2048, 3072, nullptr, nullptr, nullptr, nullptr);
}

// Round 15
// 329.659 us; speedup vs baseline: 1.0784x; 1.0382x over previous
//
#include <hip/hip_runtime.h>

typedef __bf16 bf16x8 __attribute__((ext_vector_type(8)));
typedef float f32x4 __attribute__((ext_vector_type(4)));

typedef __attribute__((address_space(1))) void gvoid;
typedef __attribute__((address_space(3))) void lvoid;

__device__ __forceinline__ void gl_lds16(const void* g, void* l) {
    __builtin_amdgcn_global_load_lds((gvoid*)g, (lvoid*)l, 16, 0, 0);
}

// NaN/inf scrub for epilogues only.
__device__ __forceinline__ float fin(float v) {
    v = (v == v) ? v : 0.f;
    return fminf(fmaxf(v, -3.0e38f), 3.0e38f);
}

__device__ __forceinline__ bf16x8 cvt8(float4 a, float4 b) {
    bf16x8 r;
    r[0] = (__bf16)a.x; r[1] = (__bf16)a.y; r[2] = (__bf16)a.z; r[3] = (__bf16)a.w;
    r[4] = (__bf16)b.x; r[5] = (__bf16)b.y; r[6] = (__bf16)b.z; r[7] = (__bf16)b.w;
    return r;
}

__device__ __forceinline__ void cvt_range(const float* __restrict__ in,
                                          __bf16* __restrict__ out, int i) {
    const float4* p = (const float4*)in + (size_t)i * 2;
    ((bf16x8*)out)[i] = cvt8(p[0], p[1]);
}

#define SCALE_LOG2E 0.12751666797152713f

// ---------------------------------------------------------------------------
// prep: fused cvt(x)+gate, cvt(w_qkv), rope table. (unchanged from round 8)
// ---------------------------------------------------------------------------
__global__ __launch_bounds__(256) void prep_kernel(const float* __restrict__ x,
                                                   const float* __restrict__ wqkv,
                                                   __bf16* __restrict__ xb,
                                                   __bf16* __restrict__ wqb,
                                                   const float* __restrict__ wg,
                                                   const float* __restrict__ bg,
                                                   float* __restrict__ gate,
                                                   float2* __restrict__ ropet) {
    __shared__ float gp[4][16];
    int bid = blockIdx.x, tid = threadIdx.x;
    if (bid < 4096) {
        // ---- one (b,s) row: cvt + gate ----
        int lane = tid & 63, wave = tid >> 6;
        const float4* xr = (const float4*)(x + (size_t)bid * 2048);
        float4 p0 = xr[tid * 2], p1 = xr[tid * 2 + 1];
        ((bf16x8*)xb)[bid * 256 + tid] = cvt8(p0, p1);
#pragma unroll
        for (int h = 0; h < 16; ++h) {
            const float4* wr = (const float4*)(wg + (size_t)h * 2048);
            float4 w0 = wr[tid * 2], w1 = wr[tid * 2 + 1];
            float acc = p0.x * w0.x + p0.y * w0.y + p0.z * w0.z + p0.w * w0.w +
                        p1.x * w1.x + p1.y * w1.y + p1.z * w1.z + p1.w * w1.w;
#pragma unroll
            for (int m = 1; m < 64; m <<= 1) acc += __shfl_xor(acc, m);
            if (lane == 0) gp[wave][h] = acc;
        }
        __syncthreads();
        if (tid < 16) {
            int s = bid & 2047, b = bid >> 11;
            float z = gp[0][tid] + gp[1][tid] + gp[2][tid] + gp[3][tid] + bg[tid];
            gate[((size_t)b * 16 + tid) * 2048 + s] = 1.f / (1.f + __expf(-z));
        }
        return;
    }
    if (bid < 7168) {
        cvt_range(wqkv, wqb, (bid - 4096) * 256 + tid);
        return;
    }
    // ---- rope table: idx = s*64 + d0 ----
    int idx = (bid - 7168) * 256 + tid;
    int s = idx >> 6, d0 = idx & 63;
    float freq = (float)s * __expf(-(float)d0 * (9.2103403719761836f / 64.0f));
    ropet[idx] = make_float2(cosf(freq), sinf(freq));
}

// ---------------------------------------------------------------------------
// wo_cvt: w_o fp32 -> bf16 into the Kb/Vtb region (dead after attn).
// ---------------------------------------------------------------------------
__global__ __launch_bounds__(256) void wo_cvt_kernel(const float* __restrict__ wo,
                                                     __bf16* __restrict__ wob) {
    cvt_range(wo, wob, blockIdx.x * 256 + threadIdx.x);
}

// ---------------------------------------------------------------------------
// GEMM, ROUND-14: 128x128 tiles (64 KiB LDS, 2 blocks/CU) with phases
// MERGED 4 -> 2 per K-tile. r13 showed MfmaUtil 24.6% with everything else
// idle: the 8-phase skeleton at 128x128 fired only 4 MFMA per barrier.
// Merged phase = one N-half over BOTH M-halves = 8 MFMA per cluster, half
// the barriers. Second A-fragment buffer (af2) carries the other M-half.
//
// Merged schedule (per 2 K-tiles u=2i buf0, u+1 buf1), re-derived stage
// placement + counted vmcnt (retire-before-read audited incl. prologue):
//   PhA: read A0h0,A0h1,B0h0; MMA nh=0; stage B1h0,B1h1(u+1);  vmcnt(4)
//   PhB: read B0h1;           MMA nh=1; stage A0h0,A0h1,B0h0(u+2); vmcnt(4)
//   PhC: read A1h0,A1h1,B1h0; MMA nh=0; stage B0h1(u+2);       vmcnt(4)
//   PhD: read B1h1;           MMA nh=1; stage A1h0,A1h1(u+3);  vmcnt(3)
// Prologue: A0h0,A0h1,B0h0,B0h1(t0), A1h0,A1h1(t1); vmcnt(3).
// Epilogue (EPI=1): BN=128 = one head. xblk = col0/128: 0-15 Q in place,
// 16-19 K -> Kx, 20-23 V plain. T1 XCD swizzle + r10 fragment swizzle kept.
// ---------------------------------------------------------------------------
template <int WMT, int WNT, int EPI, typename TC>
__global__ __launch_bounds__(512, 4) void gemm8p(const __bf16* __restrict__ A,
                                                 const __bf16* __restrict__ B,
                                                 TC* __restrict__ C,
                                                 int M, int N, int K, int ldA,
                                                 const float* __restrict__ qw,
                                                 const float* __restrict__ kw,
                                                 const float2* __restrict__ ropet,
                                                 __bf16* __restrict__ Kx) {
    constexpr int BM = WMT * 32;   // WARPS_M = 2
    constexpr int BN = WNT * 64;   // WARPS_N = 4
    constexpr int LA = BM / 128;   // gl_lds16 per thread per A half-tile
    constexpr int LB = BN / 128;

    __shared__ __align__(16) __bf16 As[2][BM * 64];
    __shared__ __align__(16) __bf16 Bs[2][BN * 64];

    const int tid = threadIdx.x;
    const int lane = tid & 63, wave = tid >> 6;
    const int wm = wave >> 2, wn = wave & 3;
    const int quad = lane >> 4, mrow = lane & 15;

    // T1 bijective XCD swizzle (nwg % 8 == 0 for both instantiations).
    const int nbx = gridDim.x;
    const int nwg = nbx * gridDim.y;
    const int orig = (int)blockIdx.y * nbx + (int)blockIdx.x;
    const int wg = (orig & 7) * (nwg >> 3) + (orig >> 3);
    const size_t row0 = (size_t)(wg / nbx) * BM;
    const size_t col0 = (size_t)(wg % nbx) * BN;

    // Inverse-swizzled global source offsets for linear gl_lds staging.
    size_t sA[LA], sB[LB];
    int dA[LA], dB[LB];
#pragma unroll
    for (int c = 0; c < LA; ++c) {
        int q = c * 512 + tid;
        int a = q * 16;                       // linear LDS byte offset
        int p = (a >> 4) & 63;                // slot within 1024B subtile
        int rowl = (a >> 11) * 16 + (p >> 2);
        int g = (p & 3) ^ ((p >> 3) & 3);     // logical k-group at this slot
        int col = ((a >> 10) & 1) * 32 + g * 8;
        sA[c] = (size_t)rowl * ldA + col;
        dA[c] = q * 8;
    }
#pragma unroll
    for (int c = 0; c < LB; ++c) {
        int q = c * 512 + tid;
        int a = q * 16;
        int p = (a >> 4) & 63;
        int rowl = (a >> 11) * 16 + (p >> 2);
        int g = (p & 3) ^ ((p >> 3) & 3);
        int col = ((a >> 10) & 1) * 32 + g * 8;
        sB[c] = (size_t)rowl * K + col;
        dB[c] = q * 8;
    }

    const __bf16* Ag = A + row0 * ldA;
    const __bf16* Bg = B + col0 * K;

    f32x4 acc[WMT][WNT];
#pragma unroll
    for (int i = 0; i < WMT; ++i)
#pragma unroll
        for (int j = 0; j < WNT; ++j) acc[i][j] = (f32x4){0.f, 0.f, 0.f, 0.f};

    // Bank-balanced per-lane ds_read base (slot = mrow*4 + quad^((mrow>>1)&3)).
    const int abase = mrow * 64 + ((quad ^ ((mrow >> 1) & 3)) * 16);

    bf16x8 af[WMT / 2][2], af2[WMT / 2][2], bf[WNT / 2][2];

#define STA8(buf, h, kt)                                                        \
    _Pragma("unroll") for (int c = 0; c < LA; ++c)                              \
        gl_lds16(Ag + (size_t)(h) * (BM / 2) * ldA + (size_t)(kt) * 64 + sA[c], \
                 &As[buf][(h) * (BM / 2) * 64 + dA[c]])

#define STB8(buf, h, kt)                                                        \
    _Pragma("unroll") for (int c = 0; c < LB; ++c)                              \
        gl_lds16(Bg + (size_t)(h) * (BN / 2) * K + (size_t)(kt) * 64 + sB[c],   \
                 &Bs[buf][(h) * (BN / 2) * 64 + dB[c]])

#define LDA8(dst, buf, mh)                                                      \
    _Pragma("unroll") for (int m2 = 0; m2 < WMT / 2; ++m2)                      \
    _Pragma("unroll") for (int s = 0; s < 2; ++s)                               \
        dst[m2][s] = *(const bf16x8*)((const char*)&As[buf][0] +                \
            ((((mh) * (WMT / 2) + m2) * 2 + wm) * 2 + s) * 1024 + abase)

#define LDB8(buf, nh)                                                           \
    _Pragma("unroll") for (int n2 = 0; n2 < WNT / 2; ++n2)                      \
    _Pragma("unroll") for (int s = 0; s < 2; ++s)                               \
        bf[n2][s] = *(const bf16x8*)((const char*)&Bs[buf][0] +                 \
            ((((nh) * (WNT / 2) + n2) * 4 + wn) * 2 + s) * 1024 + abase)

// 8-MFMA cluster: one N-half (nh), both M-halves (af = mh0, af2 = mh1).
#define MMA16(nh)                                                               \
    _Pragma("unroll") for (int m2 = 0; m2 < WMT / 2; ++m2)                      \
    _Pragma("unroll") for (int n2 = 0; n2 < WNT / 2; ++n2)                      \
    _Pragma("unroll") for (int s = 0; s < 2; ++s) {                             \
        acc[m2][(nh) * (WNT / 2) + n2] =                                        \
            __builtin_amdgcn_mfma_f32_16x16x32_bf16(                            \
                af[m2][s], bf[n2][s],                                           \
                acc[m2][(nh) * (WNT / 2) + n2], 0, 0, 0);                       \
        acc[(WMT / 2) + m2][(nh) * (WNT / 2) + n2] =                            \
            __builtin_amdgcn_mfma_f32_16x16x32_bf16(                            \
                af2[m2][s], bf[n2][s],                                          \
                acc[(WMT / 2) + m2][(nh) * (WNT / 2) + n2], 0, 0, 0);           \
    }

#define BAR8 __builtin_amdgcn_s_barrier()

#define PHASE_TAIL(nh)                                                          \
    __builtin_amdgcn_s_barrier();                                               \
    asm volatile("s_waitcnt lgkmcnt(0)" ::: "memory");                          \
    __builtin_amdgcn_sched_barrier(0);                                          \
    __builtin_amdgcn_s_setprio(1);                                              \
    MMA16(nh);                                                                  \
    __builtin_amdgcn_s_setprio(0)

    const int NT = K / 64;

    // Prologue: tile0 full (A0h0,A0h1,B0h0,B0h1) + tile1 A halves.
    STA8(0, 0, 0);
    STA8(0, 1, 0);
    STB8(0, 0, 0);
    STB8(0, 1, 0);
    STA8(1, 0, 1);
    STA8(1, 1, 1);
    asm volatile("s_waitcnt vmcnt(3)" ::: "memory");
    BAR8;

    for (int i = 0; i < NT / 2; ++i) {
        const int u = 2 * i;
        const int k2 = (u + 2 < NT) ? u + 2 : NT - 1;
        const int k3 = (u + 3 < NT) ? u + 3 : NT - 1;
        // ---- PhA: tile u, N-half 0 ----
        LDA8(af, 0, 0); LDA8(af2, 0, 1); LDB8(0, 0);
        STB8(1, 0, u + 1); STB8(1, 1, u + 1);
        PHASE_TAIL(0);
        asm volatile("s_waitcnt vmcnt(4)" ::: "memory"); BAR8;
        // ---- PhB: tile u, N-half 1 ----
        LDB8(0, 1);
        STA8(0, 0, k2); STA8(0, 1, k2); STB8(0, 0, k2);
        PHASE_TAIL(1);
        asm volatile("s_waitcnt vmcnt(4)" ::: "memory"); BAR8;
        // ---- PhC: tile u+1, N-half 0 ----
        LDA8(af, 1, 0); LDA8(af2, 1, 1); LDB8(1, 0);
        STB8(0, 1, k2);
        PHASE_TAIL(0);
        asm volatile("s_waitcnt vmcnt(4)" ::: "memory"); BAR8;
        // ---- PhD: tile u+1, N-half 1 ----
        LDB8(1, 1);
        STA8(1, 0, k3); STA8(1, 1, k3);
        PHASE_TAIL(1);
        asm volatile("s_waitcnt vmcnt(3)" ::: "memory"); BAR8;
    }
    asm volatile("s_waitcnt vmcnt(0)" ::: "memory");

#undef STA8
#undef STB8
#undef LDA8
#undef LDB8
#undef MMA16
#undef BAR8
#undef PHASE_TAIL

    if constexpr (EPI) {
        int xblk = (int)(col0 >> 7);  // BN=128: one head per tile
        if (xblk < 20) {
            // ---- fused Q/K normrope from fp32 accumulators ----
            // d = nt*64 + d0, d0 = wn*16+mrow; acc[mt][0]/acc[mt][1] are the
            // rope pair (d, d+64).
            __syncthreads();  // LDS quiescent; reuse As for the reduce
            float* sums = (float*)&As[0][0];  // [wm][mt][quad][wn][r] = 512 f32
            const int d0 = wn * 16 + mrow;
#pragma unroll
            for (int mt = 0; mt < WMT; ++mt) {
                f32x4 p;
#pragma unroll
                for (int r = 0; r < 4; ++r)
                    p[r] = acc[mt][0][r] * acc[mt][0][r] +
                           acc[mt][1][r] * acc[mt][1][r];
#pragma unroll
                for (int m = 1; m < 16; m <<= 1)
#pragma unroll
                    for (int r = 0; r < 4; ++r) p[r] += __shfl_xor(p[r], m);
                if (mrow == 0) {
                    int idx = (((wm * 4 + mt) * 4 + quad) * 4 + wn) * 4;
#pragma unroll
                    for (int r = 0; r < 4; ++r) sums[idx + r] = p[r];
                }
            }
            __syncthreads();
            const bool isQ = (xblk < 16);
            const float* w = isQ ? qw : kw;
            float w1 = w[d0], w2 = w[d0 + 64];
            float osc = isQ ? SCALE_LOG2E : 1.0f;
            int kvh = xblk - 16;
#pragma unroll
            for (int mt = 0; mt < WMT; ++mt) {
                int rbase = (int)row0 + (mt * 2 + wm) * 16 + quad * 4;
                int ib = ((wm * 4 + mt) * 4 + quad) * 16;
                f32x4 sv = *(const f32x4*)&sums[ib] + *(const f32x4*)&sums[ib + 4] +
                           *(const f32x4*)&sums[ib + 8] + *(const f32x4*)&sums[ib + 12];
#pragma unroll
                for (int r = 0; r < 4; ++r) {
                    int row = rbase + r;
                    int s_ = row & 2047, b_ = row >> 11;
                    float inv = rsqrtf(sv[r] * (1.0f / 128.0f) + 1e-5f);
                    float2 cs = ropet[s_ * 64 + d0];
                    float y1 = acc[mt][0][r] * inv * w1;
                    float y2 = acc[mt][1][r] * inv * w2;
                    float v1 = (y1 * cs.x - y2 * cs.y) * osc;
                    float v2 = (y1 * cs.y + y2 * cs.x) * osc;
                    if (isQ) {
                        size_t base = (size_t)row * N + col0 + d0;
                        C[base] = (TC)v1;
                        C[base + 64] = (TC)v2;
                    } else {
                        __bf16* dst = Kx + (((size_t)(b_ * 4 + kvh) * 2048 + s_) << 7);
                        dst[d0] = (__bf16)v1;
                        dst[d0 + 64] = (__bf16)v2;
                    }
                }
            }
            return;  // K never written to qkv; Q written normed in place
        }
    }

#pragma unroll
    for (int mt = 0; mt < WMT; ++mt)
#pragma unroll
        for (int nt = 0; nt < WNT; ++nt)
#pragma unroll
            for (int r = 0; r < 4; ++r) {
                size_t row = row0 + (mt * 2 + wm) * 16 + quad * 4 + r;
                size_t col = col0 + (nt * 4 + wn) * 16 + mrow;
                C[row * N + col] = (TC)fin(acc[mt][nt][r]);
            }
}

// ---------------------------------------------------------------------------
// mid: V transpose only (Q and K normed in the gemm epilogue). 512 blocks.
// ---------------------------------------------------------------------------
__global__ __launch_bounds__(256) void mid_kernel(const __bf16* __restrict__ qkv,
                                                  __bf16* __restrict__ Vt) {
    __shared__ __align__(16) __bf16 tile[64][72];
    int v = blockIdx.x, t = threadIdx.x;
    int st0 = (v & 31) * 64;
    int dblk = (v >> 5) & 1;
    int bz = v >> 6;
    int b = bz >> 2, kv = bz & 3;
    const __bf16* src = qkv + (size_t)(b * 2048 + st0) * 3072 + 2560 + kv * 128 + dblk * 64;
#pragma unroll
    for (int it = 0; it < 2; ++it) {
        int row = it * 32 + (t >> 3);
        int ch = t & 7;
        *(bf16x8*)&tile[row][ch * 8] = *(const bf16x8*)(src + (size_t)row * 3072 + ch * 8);
    }
    __syncthreads();
    __bf16* dst = Vt + ((size_t)(b * 4 + kv) * 128 + dblk * 64) * 2048 + st0;
#pragma unroll
    for (int it = 0; it < 2; ++it) {
        int drow = it * 32 + (t >> 3);
        int sch = t & 7;
        bf16x8 vv;
#pragma unroll
        for (int j = 0; j < 8; ++j) vv[j] = tile[sch * 8 + j][drow];
        *(bf16x8*)(dst + (size_t)drow * 2048 + sch * 8) = vv;
    }
}

// ---------------------------------------------------------------------------
// Flash attention v10 (unchanged from round 12): P-swizzle, MFMA-ones row
// sums, key-split-in-block, conflict-free merge; Q from qkv (stride 3072),
// O written in place over the block's own Q region.
// ---------------------------------------------------------------------------
#define FIXED_M 20.0f

#define MFMA16(a, b, c) __builtin_amdgcn_mfma_f32_16x16x32_bf16(a, b, c, 0, 0, 0)

__device__ __forceinline__ int pswz(int e) { return e ^ (((e >> 7) & 1) << 4); }

template <int MODE>  // 0: both full; 1: h0 diag + h1 full; 2: h1 diag only
__device__ __forceinline__ void attn_step(const __bf16* Kl, const __bf16* Vl,
                                          int ws, int quad, int mrow,
                                          const bf16x8* aq0, const bf16x8* aq1,
                                          f32x4* o0, f32x4* o1,
                                          f32x4& lf0, f32x4& lf1,
                                          __bf16* Pw) {
    bf16x8 ones;
#pragma unroll
    for (int i = 0; i < 8; ++i) ones[i] = (__bf16)1.0f;

    f32x4 sc0[4], sc1[4];
    __builtin_amdgcn_s_setprio(1);
#pragma unroll
    for (int jt = 0; jt < 4; ++jt) {
        f32x4 s0 = (f32x4){0.f, 0.f, 0.f, 0.f};
        f32x4 s1 = (f32x4){0.f, 0.f, 0.f, 0.f};
#pragma unroll
        for (int dt = 0; dt < 4; ++dt) {
            bf16x8 bk = *(const bf16x8*)&Kl[((dt * 4 + quad) * 64 + jt * 16 + mrow) * 8];
            if (MODE < 2) s0 = MFMA16(aq0[dt], bk, s0);
            s1 = MFMA16(aq1[dt], bk, s1);
        }
        sc0[jt] = s0;
        sc1[jt] = s1;
    }
    __builtin_amdgcn_s_setprio(0);

    if (MODE == 1) {
        int rloc = ws * 16 + quad * 4;
#pragma unroll
        for (int jt = 0; jt < 4; ++jt)
#pragma unroll
            for (int r = 0; r < 4; ++r)
                if (jt * 16 + mrow > rloc + r) sc0[jt][r] = -1e30f;
    }
    if (MODE == 2) {
        int rloc = ws * 16 + quad * 4;
#pragma unroll
        for (int jt = 0; jt < 4; ++jt)
#pragma unroll
            for (int r = 0; r < 4; ++r)
                if (jt * 16 + mrow > rloc + r) sc1[jt][r] = -1e30f;
    }

    // Streaming softmax through the SHARED per-wave P buffer (h0 then h1;
    // same-wave DS ops execute in order, so the WAR on Pw is safe).
    const int rb0 = pswz(((0 * 4 + quad) * 16 + mrow) * 8);
    const int rb1 = pswz(((1 * 4 + quad) * 16 + mrow) * 8);
    bf16x8 ap0[2], ap1[2];
    if (MODE < 2) {
#pragma unroll
        for (int jt = 0; jt < 4; ++jt)
#pragma unroll
            for (int r = 0; r < 4; ++r) {
                float pv = exp2f(sc0[jt][r] - FIXED_M);
                int k = jt * 16 + mrow;
                Pw[pswz(((k >> 3) * 16 + quad * 4 + r) * 8 + (k & 7))] = (__bf16)pv;
            }
        ap0[0] = *(const bf16x8*)&Pw[rb0];
        ap0[1] = *(const bf16x8*)&Pw[rb1];
        lf0 = MFMA16(ap0[0], ones, lf0);
        lf0 = MFMA16(ap0[1], ones, lf0);
    }
#pragma unroll
    for (int jt = 0; jt < 4; ++jt)
#pragma unroll
        for (int r = 0; r < 4; ++r) {
            float pv = exp2f(sc1[jt][r] - FIXED_M);
            int k = jt * 16 + mrow;
            Pw[pswz(((k >> 3) * 16 + quad * 4 + r) * 8 + (k & 7))] = (__bf16)pv;
        }
    ap1[0] = *(const bf16x8*)&Pw[rb0];
    ap1[1] = *(const bf16x8*)&Pw[rb1];
    lf1 = MFMA16(ap1[0], ones, lf1);
    lf1 = MFMA16(ap1[1], ones, lf1);

    __builtin_amdgcn_s_setprio(1);
#pragma unroll
    for (int d2 = 0; d2 < 8; ++d2)
#pragma unroll
        for (int ks = 0; ks < 2; ++ks) {
            bf16x8 bv = *(const bf16x8*)&Vl[((ks * 4 + quad) * 128 + d2 * 16 + mrow) * 8];
            if (MODE < 2) o0[d2] = MFMA16(ap0[ks], bv, o0[d2]);
            o1[d2] = MFMA16(ap1[ks], bv, o1[d2]);
        }
    __builtin_amdgcn_s_setprio(0);
}

__global__ __launch_bounds__(512, 2) void attn_kernel(__bf16* __restrict__ qkvO,
                                                      const __bf16* __restrict__ Kx,
                                                      const __bf16* __restrict__ Vt,
                                                      const float* __restrict__ gate) {
    __shared__ __align__(16) __bf16 Kl[2][2][64 * 128];  // [stream][buf]
    __shared__ __align__(16) __bf16 Vl[2][2][128 * 64];  // [stream][buf]
    __shared__ __align__(16) __bf16 Pl[8][1024];
    int tid = threadIdx.x, lane = tid & 63, wave = tid >> 6;

    int ws = wave & 3, st = wave >> 2;  // row-group, stream
    int quad = lane >> 4, mrow = lane & 15;
    __bf16* Pw = &Pl[wave][0];

    int idx = blockIdx.x;
    int qb = 15 - (idx >> 5);  // longest items dispatch first (backfill)
    int h = idx & 15, b = (idx >> 4) & 1;
    int kvh = h >> 2;

    // Staging: threads 0-255 stage the even-stream tile, 256-511 the odd.
    int sst = tid >> 8, lt = tid & 255;
    const __bf16* kbase = Kx + (size_t)(b * 4 + kvh) * 2048 * 128 + (lt & 63) * 128 + (lt >> 6) * 8;
    const __bf16* vbase = Vt + (size_t)(b * 4 + kvh) * 128 * 2048 + (lt & 127) * 2048 + (lt >> 7) * 8;
    int ldst = lt * 8;

    auto STAGE = [&](int buf, int tile) {
        const __bf16* kp = kbase + (size_t)tile * 8192;
        const __bf16* vp = vbase + (size_t)tile * 64;
#pragma unroll
        for (int c = 0; c < 4; ++c) gl_lds16(kp + 32 * c, &Kl[sst][buf][ldst + 2048 * c]);
#pragma unroll
        for (int c = 0; c < 4; ++c) gl_lds16(vp + 16 * c, &Vl[sst][buf][ldst + 2048 * c]);
    };

    STAGE(0, sst);  // even stream: tile 0; odd stream: tile 1

    // Q from qkv (normed+roped in the gemm epilogue), row stride 3072.
    const __bf16* Qh = qkvO + (size_t)(b * 2048 + qb * 128 + ws * 16 + mrow) * 3072 + h * 128;
    bf16x8 aq0[4], aq1[4];
#pragma unroll
    for (int dt = 0; dt < 4; ++dt) {
        aq0[dt] = *(const bf16x8*)(Qh + dt * 32 + quad * 8);
        aq1[dt] = *(const bf16x8*)(Qh + (size_t)64 * 3072 + dt * 32 + quad * 8);
    }

    f32x4 o0[8], o1[8];
#pragma unroll
    for (int d2 = 0; d2 < 8; ++d2) {
        o0[d2] = (f32x4){0.f, 0.f, 0.f, 0.f};
        o1[d2] = (f32x4){0.f, 0.f, 0.f, 0.f};
    }
    f32x4 lf0 = (f32x4){0.f, 0.f, 0.f, 0.f}, lf1 = (f32x4){0.f, 0.f, 0.f, 0.f};

    __syncthreads();  // tiles 0,1 visible (barrier drains gl_lds)

    int cur = 0;
    for (int kt = 0; kt < qb; ++kt) {
        STAGE(cur ^ 1, 2 * (kt + 1) + sst);  // prefetch both streams' next
        attn_step<0>(Kl[st][cur], Vl[st][cur], ws, quad, mrow, aq0, aq1, o0, o1, lf0, lf1, Pw);
        __syncthreads();
        cur ^= 1;
    }
    // Last step: even stream tile 2qb = MODE1; odd stream tile 2qb+1 = MODE2.
    if (st == 0)
        attn_step<1>(Kl[0][cur], Vl[0][cur], ws, quad, mrow, aq0, aq1, o0, o1, lf0, lf1, Pw);
    else
        attn_step<2>(Kl[1][cur], Vl[1][cur], ws, quad, mrow, aq0, aq1, o0, o1, lf0, lf1, Pw);

    // ---- in-block fp32 merge, conflict-free [slot][lane] layout ----
    __syncthreads();  // all waves done with K/V LDS
    f32x4* mo = (f32x4*)&Kl[0][0][0];   // 16 slots x 256 lanes x f32x4 = 64 KB
    float* ml = (float*)&Pl[0][0];      // 8 slots x 256 lanes x f32 = 8 KB
    int mlane = ws * 64 + lane;
    if (st == 1) {
#pragma unroll
        for (int d2 = 0; d2 < 8; ++d2) {
            mo[d2 * 256 + mlane] = o0[d2];
            mo[(d2 + 8) * 256 + mlane] = o1[d2];
        }
#pragma unroll
        for (int r = 0; r < 4; ++r) {
            ml[r * 256 + mlane] = lf0[r];
            ml[(r + 4) * 256 + mlane] = lf1[r];
        }
    }
    __syncthreads();
    if (st == 0) {
#pragma unroll
        for (int d2 = 0; d2 < 8; ++d2) {
            o0[d2] += mo[d2 * 256 + mlane];
            o1[d2] += mo[(d2 + 8) * 256 + mlane];
        }
#pragma unroll
        for (int r = 0; r < 4; ++r) {
            lf0[r] += ml[r * 256 + mlane];
            lf1[r] += ml[(r + 4) * 256 + mlane];
        }
#pragma unroll
        for (int hf = 0; hf < 2; ++hf) {
            f32x4* oo = hf ? o1 : o0;
            f32x4 ll = hf ? lf1 : lf0;
            int srow0 = qb * 128 + hf * 64 + ws * 16 + quad * 4;
            float gv[4], il[4];
#pragma unroll
            for (int r = 0; r < 4; ++r) {
                gv[r] = gate[((size_t)b * 16 + h) * 2048 + srow0 + r];
                il[r] = 1.0f / fmaxf(ll[r], 1e-30f);
            }
            // O in place over this block's own Q region (stride 3072).
#pragma unroll
            for (int d2 = 0; d2 < 8; ++d2)
#pragma unroll
                for (int r = 0; r < 4; ++r)
                    qkvO[(size_t)(b * 2048 + srow0 + r) * 3072 + h * 128 + d2 * 16 + mrow] =
                        (__bf16)fin(oo[d2][r] * il[r] * gv[r]);
        }
    }
}

// ---------------------------------------------------------------------------
// Memory plan (ws <= 33,554,432 B; d_out doubles as scratch where safe).
//   d_out: xb[0,16.7M) + wqb[16.7,29.36M) + gateb[29.36M,+256K) +
//          ropet[29.62M,+1M) -> all dead after attn -> out fp32 [0,33.5M)
//   ws: qkv[0,25.2M): Q-cols normed by gQKV epi, overwritten in place by
//       attn's O; V-cols dead after mid; K-col range never written.
//       Kb[25.2,29.4M) / Vtb[29.4,33.5M) live through attn, then wob over
//       [25.2,33.5M) (wo_cvt after attn).
// Launch graph (6): prep -> gemmQKV(+Q/K-epi) -> mid(vtrans) -> attn ->
//                   wo_cvt -> gemmOut(A=qkv ldA=3072)
// ---------------------------------------------------------------------------
extern "C" void kernel_launch(void* const* d_in, const int* in_sizes, int n_in,
                              void* d_out, int out_size, void* d_ws, size_t ws_size,
                              hipStream_t stream) {
    const float* x = (const float*)d_in[0];
    const float* w_qkv = (const float*)d_in[1];
    const float* q_norm_w = (const float*)d_in[2];
    const float* k_norm_w = (const float*)d_in[3];
    const float* w_gate = (const float*)d_in[4];
    const float* b_gate = (const float*)d_in[5];
    const float* w_o = (const float*)d_in[6];
    float* out = (float*)d_out;

    char* ws = (char*)d_ws;
    char* od = (char*)d_out;
    __bf16* xb = (__bf16*)(od);
    __bf16* wqb = (__bf16*)(od + 16777216);
    float* gateb = (float*)(od + 29360128);
    float2* ropet = (float2*)(od + 29622272);
    __bf16* qkv = (__bf16*)(ws);
    __bf16* Kb = (__bf16*)(ws + 25165824);
    __bf16* Vtb = (__bf16*)(ws + 29360128);
    __bf16* wob = (__bf16*)(ws + 25165824);  // over Kb+Vtb, dead post-attn

    // prep: cvt x + gate [0,4096) + cvt w_qkv [4096,7168) + rope table [7168,7680)
    prep_kernel<<<7680, 256, 0, stream>>>(x, w_qkv, xb, wqb, w_gate, b_gate, gateb, ropet);
    // QKV GEMM: 128x128 tile, grid 24x32 = 768 blocks (2 blocks/CU).
    gemm8p<4, 2, 1, __bf16><<<dim3(3072 / 128, 4096 / 128), 512, 0, stream>>>(
        xb, wqb, qkv, 4096, 3072, 2048, 2048, q_norm_w, k_norm_w, ropet, Kb);
    // mid: vtrans only (512 blocks)
    mid_kernel<<<512, 256, 0, stream>>>(qkv, Vtb);
    // attn: Q from qkv, O in place over Q
    attn_kernel<<<512, 512, 0, stream>>>(qkv, Kb, Vtb, gateb);
    // w_o cvt into the dead Kb/Vtb region
    wo_cvt_kernel<<<2048, 256, 0, stream>>>(w_o, wob);
    // Output GEMM: 128x128 tile, grid 16x32 = 512 blocks; A = qkv ldA=3072.
    gemm8p<4, 2, 0, float><<<dim3(2048 / 128, 4096 / 128), 512, 0, stream>>>(
        qkv, wob, out, 4096, 2048, 2048, 3072, nullptr, nullptr, nullptr, nullptr);
}

// Round 16
// 311.912 us; speedup vs baseline: 1.1398x; 1.0569x over previous
//
#include <hip/hip_runtime.h>

typedef __bf16 bf16x8 __attribute__((ext_vector_type(8)));
typedef float f32x4 __attribute__((ext_vector_type(4)));

typedef __attribute__((address_space(1))) void gvoid;
typedef __attribute__((address_space(3))) void lvoid;

__device__ __forceinline__ void gl_lds16(const void* g, void* l) {
    __builtin_amdgcn_global_load_lds((gvoid*)g, (lvoid*)l, 16, 0, 0);
}

// NaN/inf scrub for epilogues only.
__device__ __forceinline__ float fin(float v) {
    v = (v == v) ? v : 0.f;
    return fminf(fmaxf(v, -3.0e38f), 3.0e38f);
}

__device__ __forceinline__ bf16x8 cvt8(float4 a, float4 b) {
    bf16x8 r;
    r[0] = (__bf16)a.x; r[1] = (__bf16)a.y; r[2] = (__bf16)a.z; r[3] = (__bf16)a.w;
    r[4] = (__bf16)b.x; r[5] = (__bf16)b.y; r[6] = (__bf16)b.z; r[7] = (__bf16)b.w;
    return r;
}

__device__ __forceinline__ void cvt_range(const float* __restrict__ in,
                                          __bf16* __restrict__ out, int i) {
    const float4* p = (const float4*)in + (size_t)i * 2;
    ((bf16x8*)out)[i] = cvt8(p[0], p[1]);
}

#define SCALE_LOG2E 0.12751666797152713f

// ---------------------------------------------------------------------------
// prep (round 15: gate REMOVED — now a 16-col appendage of the QKV GEMM).
// Pure streaming: cvt x [0,4096), cvt w_qkv [4096,7168), cvt w_gate into
// wqb rows [3072,3088) [7168,7184), rope table [7184,7696).
// ---------------------------------------------------------------------------
__global__ __launch_bounds__(256) void prep_kernel(const float* __restrict__ x,
                                                   const float* __restrict__ wqkv,
                                                   const float* __restrict__ wg,
                                                   __bf16* __restrict__ xb,
                                                   __bf16* __restrict__ wqb,
                                                   float2* __restrict__ ropet) {
    int bid = blockIdx.x, tid = threadIdx.x;
    if (bid < 4096) {
        cvt_range(x, xb, bid * 256 + tid);
        return;
    }
    if (bid < 7168) {
        cvt_range(wqkv, wqb, (bid - 4096) * 256 + tid);
        return;
    }
    if (bid < 7184) {
        // w_gate rows appended as wqb rows [3072,3088)
        cvt_range(wg, wqb + (size_t)3072 * 2048, (bid - 7168) * 256 + tid);
        return;
    }
    // ---- rope table: idx = s*64 + d0 ----
    int idx = (bid - 7184) * 256 + tid;
    int s = idx >> 6, d0 = idx & 63;
    float freq = (float)s * __expf(-(float)d0 * (9.2103403719761836f / 64.0f));
    ropet[idx] = make_float2(cosf(freq), sinf(freq));
}

// ---------------------------------------------------------------------------
// wo_cvt: w_o fp32 -> bf16 into the Kb/Vtb region (dead after attn).
// ---------------------------------------------------------------------------
__global__ __launch_bounds__(256) void wo_cvt_kernel(const float* __restrict__ wo,
                                                     __bf16* __restrict__ wob) {
    cvt_range(wo, wob, blockIdx.x * 256 + threadIdx.x);
}

// ---------------------------------------------------------------------------
// GEMM (r14 merged 2-phase schedule; see r14 comments) + r15: N (B columns)
// split from ldC (C row stride) so the QKV gemm can carry the 16-col gate
// matmul as tile column 24 (N=3200, ldC=3072):
//   xblk 0-15  Q: fp32 rmsnorm+rope x SCALE_LOG2E, in place to C.
//   xblk 16-19 K: fp32 rmsnorm+rope -> Kx.
//   xblk 20-23 V: plain C write.
//   xblk 24 gate: sigmoid(acc + bg) -> gateb for the 16 real cols (wn==0 &&
//     nt==0); B rows 3088-3199 are garbage but their NaNs stay in discarded
//     MFMA columns. No C write (cols >= 3072 don't exist at ldC=3072).
// ---------------------------------------------------------------------------
template <int WMT, int WNT, int EPI, typename TC>
__global__ __launch_bounds__(512, 4) void gemm8p(const __bf16* __restrict__ A,
                                                 const __bf16* __restrict__ B,
                                                 TC* __restrict__ C,
                                                 int M, int N, int K, int ldA, int ldC,
                                                 const float* __restrict__ qw,
                                                 const float* __restrict__ kw,
                                                 const float2* __restrict__ ropet,
                                                 __bf16* __restrict__ Kx,
                                                 const float* __restrict__ bg,
                                                 float* __restrict__ gateb) {
    constexpr int BM = WMT * 32;   // WARPS_M = 2
    constexpr int BN = WNT * 64;   // WARPS_N = 4
    constexpr int LA = BM / 128;   // gl_lds16 per thread per A half-tile
    constexpr int LB = BN / 128;

    __shared__ __align__(16) __bf16 As[2][BM * 64];
    __shared__ __align__(16) __bf16 Bs[2][BN * 64];

    const int tid = threadIdx.x;
    const int lane = tid & 63, wave = tid >> 6;
    const int wm = wave >> 2, wn = wave & 3;
    const int quad = lane >> 4, mrow = lane & 15;

    // T1 bijective XCD swizzle (nwg % 8 == 0 for all instantiations).
    const int nbx = gridDim.x;
    const int nwg = nbx * gridDim.y;
    const int orig = (int)blockIdx.y * nbx + (int)blockIdx.x;
    const int wg = (orig & 7) * (nwg >> 3) + (orig >> 3);
    const size_t row0 = (size_t)(wg / nbx) * BM;
    const size_t col0 = (size_t)(wg % nbx) * BN;

    // Inverse-swizzled global source offsets for linear gl_lds staging.
    size_t sA[LA], sB[LB];
    int dA[LA], dB[LB];
#pragma unroll
    for (int c = 0; c < LA; ++c) {
        int q = c * 512 + tid;
        int a = q * 16;                       // linear LDS byte offset
        int p = (a >> 4) & 63;                // slot within 1024B subtile
        int rowl = (a >> 11) * 16 + (p >> 2);
        int g = (p & 3) ^ ((p >> 3) & 3);     // logical k-group at this slot
        int col = ((a >> 10) & 1) * 32 + g * 8;
        sA[c] = (size_t)rowl * ldA + col;
        dA[c] = q * 8;
    }
#pragma unroll
    for (int c = 0; c < LB; ++c) {
        int q = c * 512 + tid;
        int a = q * 16;
        int p = (a >> 4) & 63;
        int rowl = (a >> 11) * 16 + (p >> 2);
        int g = (p & 3) ^ ((p >> 3) & 3);
        int col = ((a >> 10) & 1) * 32 + g * 8;
        sB[c] = (size_t)rowl * K + col;
        dB[c] = q * 8;
    }

    const __bf16* Ag = A + row0 * ldA;
    const __bf16* Bg = B + col0 * K;

    f32x4 acc[WMT][WNT];
#pragma unroll
    for (int i = 0; i < WMT; ++i)
#pragma unroll
        for (int j = 0; j < WNT; ++j) acc[i][j] = (f32x4){0.f, 0.f, 0.f, 0.f};

    // Bank-balanced per-lane ds_read base (slot = mrow*4 + quad^((mrow>>1)&3)).
    const int abase = mrow * 64 + ((quad ^ ((mrow >> 1) & 3)) * 16);

    bf16x8 af[WMT / 2][2], af2[WMT / 2][2], bf[WNT / 2][2];

#define STA8(buf, h, kt)                                                        \
    _Pragma("unroll") for (int c = 0; c < LA; ++c)                              \
        gl_lds16(Ag + (size_t)(h) * (BM / 2) * ldA + (size_t)(kt) * 64 + sA[c], \
                 &As[buf][(h) * (BM / 2) * 64 + dA[c]])

#define STB8(buf, h, kt)                                                        \
    _Pragma("unroll") for (int c = 0; c < LB; ++c)                              \
        gl_lds16(Bg + (size_t)(h) * (BN / 2) * K + (size_t)(kt) * 64 + sB[c],   \
                 &Bs[buf][(h) * (BN / 2) * 64 + dB[c]])

#define LDA8(dst, buf, mh)                                                      \
    _Pragma("unroll") for (int m2 = 0; m2 < WMT / 2; ++m2)                      \
    _Pragma("unroll") for (int s = 0; s < 2; ++s)                               \
        dst[m2][s] = *(const bf16x8*)((const char*)&As[buf][0] +                \
            ((((mh) * (WMT / 2) + m2) * 2 + wm) * 2 + s) * 1024 + abase)

#define LDB8(buf, nh)                                                           \
    _Pragma("unroll") for (int n2 = 0; n2 < WNT / 2; ++n2)                      \
    _Pragma("unroll") for (int s = 0; s < 2; ++s)                               \
        bf[n2][s] = *(const bf16x8*)((const char*)&Bs[buf][0] +                 \
            ((((nh) * (WNT / 2) + n2) * 4 + wn) * 2 + s) * 1024 + abase)

// 8-MFMA cluster: one N-half (nh), both M-halves (af = mh0, af2 = mh1).
#define MMA16(nh)                                                               \
    _Pragma("unroll") for (int m2 = 0; m2 < WMT / 2; ++m2)                      \
    _Pragma("unroll") for (int n2 = 0; n2 < WNT / 2; ++n2)                      \
    _Pragma("unroll") for (int s = 0; s < 2; ++s) {                             \
        acc[m2][(nh) * (WNT / 2) + n2] =                                        \
            __builtin_amdgcn_mfma_f32_16x16x32_bf16(                            \
                af[m2][s], bf[n2][s],                                           \
                acc[m2][(nh) * (WNT / 2) + n2], 0, 0, 0);                       \
        acc[(WMT / 2) + m2][(nh) * (WNT / 2) + n2] =                            \
            __builtin_amdgcn_mfma_f32_16x16x32_bf16(                            \
                af2[m2][s], bf[n2][s],                                          \
                acc[(WMT / 2) + m2][(nh) * (WNT / 2) + n2], 0, 0, 0);           \
    }

#define BAR8 __builtin_amdgcn_s_barrier()

#define PHASE_TAIL(nh)                                                          \
    __builtin_amdgcn_s_barrier();                                               \
    asm volatile("s_waitcnt lgkmcnt(0)" ::: "memory");                          \
    __builtin_amdgcn_sched_barrier(0);                                          \
    __builtin_amdgcn_s_setprio(1);                                              \
    MMA16(nh);                                                                  \
    __builtin_amdgcn_s_setprio(0)

    const int NT = K / 64;

    // Prologue: tile0 full (A0h0,A0h1,B0h0,B0h1) + tile1 A halves.
    STA8(0, 0, 0);
    STA8(0, 1, 0);
    STB8(0, 0, 0);
    STB8(0, 1, 0);
    STA8(1, 0, 1);
    STA8(1, 1, 1);
    asm volatile("s_waitcnt vmcnt(3)" ::: "memory");
    BAR8;

    for (int i = 0; i < NT / 2; ++i) {
        const int u = 2 * i;
        const int k2 = (u + 2 < NT) ? u + 2 : NT - 1;
        const int k3 = (u + 3 < NT) ? u + 3 : NT - 1;
        // ---- PhA: tile u, N-half 0 ----
        LDA8(af, 0, 0); LDA8(af2, 0, 1); LDB8(0, 0);
        STB8(1, 0, u + 1); STB8(1, 1, u + 1);
        PHASE_TAIL(0);
        asm volatile("s_waitcnt vmcnt(4)" ::: "memory"); BAR8;
        // ---- PhB: tile u, N-half 1 ----
        LDB8(0, 1);
        STA8(0, 0, k2); STA8(0, 1, k2); STB8(0, 0, k2);
        PHASE_TAIL(1);
        asm volatile("s_waitcnt vmcnt(4)" ::: "memory"); BAR8;
        // ---- PhC: tile u+1, N-half 0 ----
        LDA8(af, 1, 0); LDA8(af2, 1, 1); LDB8(1, 0);
        STB8(0, 1, k2);
        PHASE_TAIL(0);
        asm volatile("s_waitcnt vmcnt(4)" ::: "memory"); BAR8;
        // ---- PhD: tile u+1, N-half 1 ----
        LDB8(1, 1);
        STA8(1, 0, k3); STA8(1, 1, k3);
        PHASE_TAIL(1);
        asm volatile("s_waitcnt vmcnt(3)" ::: "memory"); BAR8;
    }
    asm volatile("s_waitcnt vmcnt(0)" ::: "memory");

#undef STA8
#undef STB8
#undef LDA8
#undef LDB8
#undef MMA16
#undef BAR8
#undef PHASE_TAIL

    if constexpr (EPI) {
        int xblk = (int)(col0 >> 7);  // BN=128: one head per tile
        if (xblk == 24) {
            // ---- fused gate: sigmoid(x . wg^T + bg) -> gateb ----
            // Real cols = tile cols 0-15 (wn==0, nt==0, all mrow).
            if (wn == 0) {
                int h = mrow;
                float bias = bg[h];
#pragma unroll
                for (int mt = 0; mt < WMT; ++mt) {
                    int rbase = (int)row0 + (mt * 2 + wm) * 16 + quad * 4;
#pragma unroll
                    for (int r = 0; r < 4; ++r) {
                        int row = rbase + r;
                        int s_ = row & 2047, b_ = row >> 11;
                        float z = acc[mt][0][r] + bias;
                        gateb[((size_t)b_ * 16 + h) * 2048 + s_] =
                            1.f / (1.f + __expf(-z));
                    }
                }
            }
            return;  // no C write (cols >= ldC)
        }
        if (xblk < 20) {
            // ---- fused Q/K normrope from fp32 accumulators ----
            __syncthreads();  // LDS quiescent; reuse As for the reduce
            float* sums = (float*)&As[0][0];  // [wm][mt][quad][wn][r] = 512 f32
            const int d0 = wn * 16 + mrow;
#pragma unroll
            for (int mt = 0; mt < WMT; ++mt) {
                f32x4 p;
#pragma unroll
                for (int r = 0; r < 4; ++r)
                    p[r] = acc[mt][0][r] * acc[mt][0][r] +
                           acc[mt][1][r] * acc[mt][1][r];
#pragma unroll
                for (int m = 1; m < 16; m <<= 1)
#pragma unroll
                    for (int r = 0; r < 4; ++r) p[r] += __shfl_xor(p[r], m);
                if (mrow == 0) {
                    int idx = (((wm * 4 + mt) * 4 + quad) * 4 + wn) * 4;
#pragma unroll
                    for (int r = 0; r < 4; ++r) sums[idx + r] = p[r];
                }
            }
            __syncthreads();
            const bool isQ = (xblk < 16);
            const float* w = isQ ? qw : kw;
            float w1 = w[d0], w2 = w[d0 + 64];
            float osc = isQ ? SCALE_LOG2E : 1.0f;
            int kvh = xblk - 16;
#pragma unroll
            for (int mt = 0; mt < WMT; ++mt) {
                int rbase = (int)row0 + (mt * 2 + wm) * 16 + quad * 4;
                int ib = ((wm * 4 + mt) * 4 + quad) * 16;
                f32x4 sv = *(const f32x4*)&sums[ib] + *(const f32x4*)&sums[ib + 4] +
                           *(const f32x4*)&sums[ib + 8] + *(const f32x4*)&sums[ib + 12];
#pragma unroll
                for (int r = 0; r < 4; ++r) {
                    int row = rbase + r;
                    int s_ = row & 2047, b_ = row >> 11;
                    float inv = rsqrtf(sv[r] * (1.0f / 128.0f) + 1e-5f);
                    float2 cs = ropet[s_ * 64 + d0];
                    float y1 = acc[mt][0][r] * inv * w1;
                    float y2 = acc[mt][1][r] * inv * w2;
                    float v1 = (y1 * cs.x - y2 * cs.y) * osc;
                    float v2 = (y1 * cs.y + y2 * cs.x) * osc;
                    if (isQ) {
                        size_t base = (size_t)row * ldC + col0 + d0;
                        C[base] = (TC)v1;
                        C[base + 64] = (TC)v2;
                    } else {
                        __bf16* dst = Kx + (((size_t)(b_ * 4 + kvh) * 2048 + s_) << 7);
                        dst[d0] = (__bf16)v1;
                        dst[d0 + 64] = (__bf16)v2;
                    }
                }
            }
            return;  // K never written to qkv; Q written normed in place
        }
    }

#pragma unroll
    for (int mt = 0; mt < WMT; ++mt)
#pragma unroll
        for (int nt = 0; nt < WNT; ++nt)
#pragma unroll
            for (int r = 0; r < 4; ++r) {
                size_t row = row0 + (mt * 2 + wm) * 16 + quad * 4 + r;
                size_t col = col0 + (nt * 4 + wn) * 16 + mrow;
                C[row * ldC + col] = (TC)fin(acc[mt][nt][r]);
            }
}

// ---------------------------------------------------------------------------
// mid: V transpose only (Q and K normed in the gemm epilogue). 512 blocks.
// ---------------------------------------------------------------------------
__global__ __launch_bounds__(256) void mid_kernel(const __bf16* __restrict__ qkv,
                                                  __bf16* __restrict__ Vt) {
    __shared__ __align__(16) __bf16 tile[64][72];
    int v = blockIdx.x, t = threadIdx.x;
    int st0 = (v & 31) * 64;
    int dblk = (v >> 5) & 1;
    int bz = v >> 6;
    int b = bz >> 2, kv = bz & 3;
    const __bf16* src = qkv + (size_t)(b * 2048 + st0) * 3072 + 2560 + kv * 128 + dblk * 64;
#pragma unroll
    for (int it = 0; it < 2; ++it) {
        int row = it * 32 + (t >> 3);
        int ch = t & 7;
        *(bf16x8*)&tile[row][ch * 8] = *(const bf16x8*)(src + (size_t)row * 3072 + ch * 8);
    }
    __syncthreads();
    __bf16* dst = Vt + ((size_t)(b * 4 + kv) * 128 + dblk * 64) * 2048 + st0;
#pragma unroll
    for (int it = 0; it < 2; ++it) {
        int drow = it * 32 + (t >> 3);
        int sch = t & 7;
        bf16x8 vv;
#pragma unroll
        for (int j = 0; j < 8; ++j) vv[j] = tile[sch * 8 + j][drow];
        *(bf16x8*)(dst + (size_t)drow * 2048 + sch * 8) = vv;
    }
}

// ---------------------------------------------------------------------------
// Flash attention v10 (unchanged from round 12): P-swizzle, MFMA-ones row
// sums, key-split-in-block, conflict-free merge; Q from qkv (stride 3072),
// O written in place over the block's own Q region.
// ---------------------------------------------------------------------------
#define FIXED_M 20.0f

#define MFMA16(a, b, c) __builtin_amdgcn_mfma_f32_16x16x32_bf16(a, b, c, 0, 0, 0)

__device__ __forceinline__ int pswz(int e) { return e ^ (((e >> 7) & 1) << 4); }

template <int MODE>  // 0: both full; 1: h0 diag + h1 full; 2: h1 diag only
__device__ __forceinline__ void attn_step(const __bf16* Kl, const __bf16* Vl,
                                          int ws, int quad, int mrow,
                                          const bf16x8* aq0, const bf16x8* aq1,
                                          f32x4* o0, f32x4* o1,
                                          f32x4& lf0, f32x4& lf1,
                                          __bf16* Pw) {
    bf16x8 ones;
#pragma unroll
    for (int i = 0; i < 8; ++i) ones[i] = (__bf16)1.0f;

    f32x4 sc0[4], sc1[4];
    __builtin_amdgcn_s_setprio(1);
#pragma unroll
    for (int jt = 0; jt < 4; ++jt) {
        f32x4 s0 = (f32x4){0.f, 0.f, 0.f, 0.f};
        f32x4 s1 = (f32x4){0.f, 0.f, 0.f, 0.f};
#pragma unroll
        for (int dt = 0; dt < 4; ++dt) {
            bf16x8 bk = *(const bf16x8*)&Kl[((dt * 4 + quad) * 64 + jt * 16 + mrow) * 8];
            if (MODE < 2) s0 = MFMA16(aq0[dt], bk, s0);
            s1 = MFMA16(aq1[dt], bk, s1);
        }
        sc0[jt] = s0;
        sc1[jt] = s1;
    }
    __builtin_amdgcn_s_setprio(0);

    if (MODE == 1) {
        int rloc = ws * 16 + quad * 4;
#pragma unroll
        for (int jt = 0; jt < 4; ++jt)
#pragma unroll
            for (int r = 0; r < 4; ++r)
                if (jt * 16 + mrow > rloc + r) sc0[jt][r] = -1e30f;
    }
    if (MODE == 2) {
        int rloc = ws * 16 + quad * 4;
#pragma unroll
        for (int jt = 0; jt < 4; ++jt)
#pragma unroll
            for (int r = 0; r < 4; ++r)
                if (jt * 16 + mrow > rloc + r) sc1[jt][r] = -1e30f;
    }

    // Streaming softmax through the SHARED per-wave P buffer (h0 then h1;
    // same-wave DS ops execute in order, so the WAR on Pw is safe).
    const int rb0 = pswz(((0 * 4 + quad) * 16 + mrow) * 8);
    const int rb1 = pswz(((1 * 4 + quad) * 16 + mrow) * 8);
    bf16x8 ap0[2], ap1[2];
    if (MODE < 2) {
#pragma unroll
        for (int jt = 0; jt < 4; ++jt)
#pragma unroll
            for (int r = 0; r < 4; ++r) {
                float pv = exp2f(sc0[jt][r] - FIXED_M);
                int k = jt * 16 + mrow;
                Pw[pswz(((k >> 3) * 16 + quad * 4 + r) * 8 + (k & 7))] = (__bf16)pv;
            }
        ap0[0] = *(const bf16x8*)&Pw[rb0];
        ap0[1] = *(const bf16x8*)&Pw[rb1];
        lf0 = MFMA16(ap0[0], ones, lf0);
        lf0 = MFMA16(ap0[1], ones, lf0);
    }
#pragma unroll
    for (int jt = 0; jt < 4; ++jt)
#pragma unroll
        for (int r = 0; r < 4; ++r) {
            float pv = exp2f(sc1[jt][r] - FIXED_M);
            int k = jt * 16 + mrow;
            Pw[pswz(((k >> 3) * 16 + quad * 4 + r) * 8 + (k & 7))] = (__bf16)pv;
        }
    ap1[0] = *(const bf16x8*)&Pw[rb0];
    ap1[1] = *(const bf16x8*)&Pw[rb1];
    lf1 = MFMA16(ap1[0], ones, lf1);
    lf1 = MFMA16(ap1[1], ones, lf1);

    __builtin_amdgcn_s_setprio(1);
#pragma unroll
    for (int d2 = 0; d2 < 8; ++d2)
#pragma unroll
        for (int ks = 0; ks < 2; ++ks) {
            bf16x8 bv = *(const bf16x8*)&Vl[((ks * 4 + quad) * 128 + d2 * 16 + mrow) * 8];
            if (MODE < 2) o0[d2] = MFMA16(ap0[ks], bv, o0[d2]);
            o1[d2] = MFMA16(ap1[ks], bv, o1[d2]);
        }
    __builtin_amdgcn_s_setprio(0);
}

__global__ __launch_bounds__(512, 2) void attn_kernel(__bf16* __restrict__ qkvO,
                                                      const __bf16* __restrict__ Kx,
                                                      const __bf16* __restrict__ Vt,
                                                      const float* __restrict__ gate) {
    __shared__ __align__(16) __bf16 Kl[2][2][64 * 128];  // [stream][buf]
    __shared__ __align__(16) __bf16 Vl[2][2][128 * 64];  // [stream][buf]
    __shared__ __align__(16) __bf16 Pl[8][1024];
    int tid = threadIdx.x, lane = tid & 63, wave = tid >> 6;

    int ws = wave & 3, st = wave >> 2;  // row-group, stream
    int quad = lane >> 4, mrow = lane & 15;
    __bf16* Pw = &Pl[wave][0];

    int idx = blockIdx.x;
    int qb = 15 - (idx >> 5);  // longest items dispatch first (backfill)
    int h = idx & 15, b = (idx >> 4) & 1;
    int kvh = h >> 2;

    // Staging: threads 0-255 stage the even-stream tile, 256-511 the odd.
    int sst = tid >> 8, lt = tid & 255;
    const __bf16* kbase = Kx + (size_t)(b * 4 + kvh) * 2048 * 128 + (lt & 63) * 128 + (lt >> 6) * 8;
    const __bf16* vbase = Vt + (size_t)(b * 4 + kvh) * 128 * 2048 + (lt & 127) * 2048 + (lt >> 7) * 8;
    int ldst = lt * 8;

    auto STAGE = [&](int buf, int tile) {
        const __bf16* kp = kbase + (size_t)tile * 8192;
        const __bf16* vp = vbase + (size_t)tile * 64;
#pragma unroll
        for (int c = 0; c < 4; ++c) gl_lds16(kp + 32 * c, &Kl[sst][buf][ldst + 2048 * c]);
#pragma unroll
        for (int c = 0; c < 4; ++c) gl_lds16(vp + 16 * c, &Vl[sst][buf][ldst + 2048 * c]);
    };

    STAGE(0, sst);  // even stream: tile 0; odd stream: tile 1

    // Q from qkv (normed+roped in the gemm epilogue), row stride 3072.
    const __bf16* Qh = qkvO + (size_t)(b * 2048 + qb * 128 + ws * 16 + mrow) * 3072 + h * 128;
    bf16x8 aq0[4], aq1[4];
#pragma unroll
    for (int dt = 0; dt < 4; ++dt) {
        aq0[dt] = *(const bf16x8*)(Qh + dt * 32 + quad * 8);
        aq1[dt] = *(const bf16x8*)(Qh + (size_t)64 * 3072 + dt * 32 + quad * 8);
    }

    f32x4 o0[8], o1[8];
#pragma unroll
    for (int d2 = 0; d2 < 8; ++d2) {
        o0[d2] = (f32x4){0.f, 0.f, 0.f, 0.f};
        o1[d2] = (f32x4){0.f, 0.f, 0.f, 0.f};
    }
    f32x4 lf0 = (f32x4){0.f, 0.f, 0.f, 0.f}, lf1 = (f32x4){0.f, 0.f, 0.f, 0.f};

    __syncthreads();  // tiles 0,1 visible (barrier drains gl_lds)

    int cur = 0;
    for (int kt = 0; kt < qb; ++kt) {
        STAGE(cur ^ 1, 2 * (kt + 1) + sst);  // prefetch both streams' next
        attn_step<0>(Kl[st][cur], Vl[st][cur], ws, quad, mrow, aq0, aq1, o0, o1, lf0, lf1, Pw);
        __syncthreads();
        cur ^= 1;
    }
    // Last step: even stream tile 2qb = MODE1; odd stream tile 2qb+1 = MODE2.
    if (st == 0)
        attn_step<1>(Kl[0][cur], Vl[0][cur], ws, quad, mrow, aq0, aq1, o0, o1, lf0, lf1, Pw);
    else
        attn_step<2>(Kl[1][cur], Vl[1][cur], ws, quad, mrow, aq0, aq1, o0, o1, lf0, lf1, Pw);

    // ---- in-block fp32 merge, conflict-free [slot][lane] layout ----
    __syncthreads();  // all waves done with K/V LDS
    f32x4* mo = (f32x4*)&Kl[0][0][0];   // 16 slots x 256 lanes x f32x4 = 64 KB
    float* ml = (float*)&Pl[0][0];      // 8 slots x 256 lanes x f32 = 8 KB
    int mlane = ws * 64 + lane;
    if (st == 1) {
#pragma unroll
        for (int d2 = 0; d2 < 8; ++d2) {
            mo[d2 * 256 + mlane] = o0[d2];
            mo[(d2 + 8) * 256 + mlane] = o1[d2];
        }
#pragma unroll
        for (int r = 0; r < 4; ++r) {
            ml[r * 256 + mlane] = lf0[r];
            ml[(r + 4) * 256 + mlane] = lf1[r];
        }
    }
    __syncthreads();
    if (st == 0) {
#pragma unroll
        for (int d2 = 0; d2 < 8; ++d2) {
            o0[d2] += mo[d2 * 256 + mlane];
            o1[d2] += mo[(d2 + 8) * 256 + mlane];
        }
#pragma unroll
        for (int r = 0; r < 4; ++r) {
            lf0[r] += ml[r * 256 + mlane];
            lf1[r] += ml[(r + 4) * 256 + mlane];
        }
#pragma unroll
        for (int hf = 0; hf < 2; ++hf) {
            f32x4* oo = hf ? o1 : o0;
            f32x4 ll = hf ? lf1 : lf0;
            int srow0 = qb * 128 + hf * 64 + ws * 16 + quad * 4;
            float gv[4], il[4];
#pragma unroll
            for (int r = 0; r < 4; ++r) {
                gv[r] = gate[((size_t)b * 16 + h) * 2048 + srow0 + r];
                il[r] = 1.0f / fmaxf(ll[r], 1e-30f);
            }
            // O in place over this block's own Q region (stride 3072).
#pragma unroll
            for (int d2 = 0; d2 < 8; ++d2)
#pragma unroll
                for (int r = 0; r < 4; ++r)
                    qkvO[(size_t)(b * 2048 + srow0 + r) * 3072 + h * 128 + d2 * 16 + mrow] =
                        (__bf16)fin(oo[d2][r] * il[r] * gv[r]);
        }
    }
}

// ---------------------------------------------------------------------------
// Memory plan (ws <= 33,554,432 B; d_out doubles as scratch where safe).
//   d_out: xb[0,16.7M) + wqb[16.7M,29.88M) (3200 rows: w_qkv + w_gate pad) +
//          gateb[29.88M,+256K) + ropet[30.15M,+1M) -> out fp32 [0,33.5M)
//   ws: qkv[0,25.2M): Q-cols normed by gQKV epi, overwritten in place by
//       attn's O; V-cols dead after mid; K-col range never written.
//       Kb[25.2,29.4M) / Vtb[29.4,33.5M) live through attn, then wob over
//       [25.2,33.5M) (wo_cvt after attn).
// Launch graph (6): prep -> gemmQKV(+Q/K/gate-epi, N=3200 ldC=3072) ->
//                   mid(vtrans) -> attn -> wo_cvt -> gemmOut(A=qkv ldA=3072)
// ---------------------------------------------------------------------------
extern "C" void kernel_launch(void* const* d_in, const int* in_sizes, int n_in,
                              void* d_out, int out_size, void* d_ws, size_t ws_size,
                              hipStream_t stream) {
    const float* x = (const float*)d_in[0];
    const float* w_qkv = (const float*)d_in[1];
    const float* q_norm_w = (const float*)d_in[2];
    const float* k_norm_w = (const float*)d_in[3];
    const float* w_gate = (const float*)d_in[4];
    const float* b_gate = (const float*)d_in[5];
    const float* w_o = (const float*)d_in[6];
    float* out = (float*)d_out;

    char* ws = (char*)d_ws;
    char* od = (char*)d_out;
    __bf16* xb = (__bf16*)(od);
    __bf16* wqb = (__bf16*)(od + 16777216);
    float* gateb = (float*)(od + 29884416);
    float2* ropet = (float2*)(od + 30146560);
    __bf16* qkv = (__bf16*)(ws);
    __bf16* Kb = (__bf16*)(ws + 25165824);
    __bf16* Vtb = (__bf16*)(ws + 29360128);
    __bf16* wob = (__bf16*)(ws + 25165824);  // over Kb+Vtb, dead post-attn

    // prep: cvt x [0,4096) + cvt w_qkv [4096,7168) + cvt w_gate [7168,7184)
    //       + rope table [7184,7696)
    prep_kernel<<<7696, 256, 0, stream>>>(x, w_qkv, w_gate, xb, wqb, ropet);
    // QKV+gate GEMM: 128x128 tile, grid 25x32 = 800 blocks; Q normed in
    // place, K -> Kb, gate -> gateb (tile col 24).
    gemm8p<4, 2, 1, __bf16><<<dim3(3200 / 128, 4096 / 128), 512, 0, stream>>>(
        xb, wqb, qkv, 4096, 3200, 2048, 2048, 3072,
        q_norm_w, k_norm_w, ropet, Kb, b_gate, gateb);
    // mid: vtrans only (512 blocks)
    mid_kernel<<<512, 256, 0, stream>>>(qkv, Vtb);
    // attn: Q from qkv, O in place over Q
    attn_kernel<<<512, 512, 0, stream>>>(qkv, Kb, Vtb, gateb);
    // w_o cvt into the dead Kb/Vtb region
    wo_cvt_kernel<<<2048, 256, 0, stream>>>(w_o, wob);
    // Output GEMM: 128x128 tile, grid 16x32 = 512 blocks; A = qkv ldA=3072.
    gemm8p<4, 2, 0, float><<<dim3(2048 / 128, 4096 / 128), 512, 0, stream>>>(
        qkv, wob, out, 4096, 2048, 2048, 3072, 2048,
        nullptr, nullptr, nullptr, nullptr, nullptr, nullptr);
}

// Round 17
// 299.873 us; speedup vs baseline: 1.1855x; 1.0401x over previous
//
#include <hip/hip_runtime.h>

typedef __bf16 bf16x8 __attribute__((ext_vector_type(8)));
typedef float f32x4 __attribute__((ext_vector_type(4)));

typedef __attribute__((address_space(1))) void gvoid;
typedef __attribute__((address_space(3))) void lvoid;

__device__ __forceinline__ void gl_lds16(const void* g, void* l) {
    __builtin_amdgcn_global_load_lds((gvoid*)g, (lvoid*)l, 16, 0, 0);
}

// NaN/inf scrub for epilogues only.
__device__ __forceinline__ float fin(float v) {
    v = (v == v) ? v : 0.f;
    return fminf(fmaxf(v, -3.0e38f), 3.0e38f);
}

__device__ __forceinline__ bf16x8 cvt8(float4 a, float4 b) {
    bf16x8 r;
    r[0] = (__bf16)a.x; r[1] = (__bf16)a.y; r[2] = (__bf16)a.z; r[3] = (__bf16)a.w;
    r[4] = (__bf16)b.x; r[5] = (__bf16)b.y; r[6] = (__bf16)b.z; r[7] = (__bf16)b.w;
    return r;
}

__device__ __forceinline__ void cvt_range(const float* __restrict__ in,
                                          __bf16* __restrict__ out, int i) {
    const float4* p = (const float4*)in + (size_t)i * 2;
    ((bf16x8*)out)[i] = cvt8(p[0], p[1]);
}

#define SCALE_LOG2E 0.12751666797152713f

// ---------------------------------------------------------------------------
// prep: pure streaming. cvt x [0,4096), cvt w_qkv [4096,7168), cvt w_gate
// into wqb rows [3072,3088) [7168,7184), rope table [7184,7696).
// ---------------------------------------------------------------------------
__global__ __launch_bounds__(256) void prep_kernel(const float* __restrict__ x,
                                                   const float* __restrict__ wqkv,
                                                   const float* __restrict__ wg,
                                                   __bf16* __restrict__ xb,
                                                   __bf16* __restrict__ wqb,
                                                   float2* __restrict__ ropet) {
    int bid = blockIdx.x, tid = threadIdx.x;
    if (bid < 4096) {
        cvt_range(x, xb, bid * 256 + tid);
        return;
    }
    if (bid < 7168) {
        cvt_range(wqkv, wqb, (bid - 4096) * 256 + tid);
        return;
    }
    if (bid < 7184) {
        // w_gate rows appended as wqb rows [3072,3088)
        cvt_range(wg, wqb + (size_t)3072 * 2048, (bid - 7168) * 256 + tid);
        return;
    }
    // ---- rope table: idx = s*64 + d0 ----
    int idx = (bid - 7184) * 256 + tid;
    int s = idx >> 6, d0 = idx & 63;
    float freq = (float)s * __expf(-(float)d0 * (9.2103403719761836f / 64.0f));
    ropet[idx] = make_float2(cosf(freq), sinf(freq));
}

// ---------------------------------------------------------------------------
// wo_cvt: w_o fp32 -> bf16 into the Kb/Vtb region (dead after attn).
// ---------------------------------------------------------------------------
__global__ __launch_bounds__(256) void wo_cvt_kernel(const float* __restrict__ wo,
                                                     __bf16* __restrict__ wob) {
    cvt_range(wo, wob, blockIdx.x * 256 + threadIdx.x);
}

// ---------------------------------------------------------------------------
// GEMM (r14 merged 2-phase schedule) + full fused epilogue (EPI=1, QKV):
//   xblk 0-15  Q: fp32 rmsnorm+rope x SCALE_LOG2E, in place to C (qkv).
//   xblk 16-19 K: fp32 rmsnorm+rope -> Kx. Never lands in qkv.
//   xblk 20-23 V (r16): TRANSPOSED IN-EPILOGUE via the block's own LDS
//     (SH as [128][136] bf16; pad 136 keeps 16B alignment for b128 readout)
//     and written straight to Vt[b][kv][d][s] — the mid/vtrans kernel and
//     V's qkv round-trip (25 MB HBM) are eliminated.
//   xblk 24 gate: sigmoid(acc + bg) -> gateb (16 real cols; B rows
//     3088-3199 garbage but confined to discarded MFMA columns).
// N (B cols, 3200) split from ldC (C row stride, 3072).
// ---------------------------------------------------------------------------
template <int WMT, int WNT, int EPI, typename TC>
__global__ __launch_bounds__(512, 4) void gemm8p(const __bf16* __restrict__ A,
                                                 const __bf16* __restrict__ B,
                                                 TC* __restrict__ C,
                                                 int M, int N, int K, int ldA, int ldC,
                                                 const float* __restrict__ qw,
                                                 const float* __restrict__ kw,
                                                 const float2* __restrict__ ropet,
                                                 __bf16* __restrict__ Kx,
                                                 const float* __restrict__ bg,
                                                 float* __restrict__ gateb,
                                                 __bf16* __restrict__ Vt) {
    constexpr int BM = WMT * 32;   // WARPS_M = 2
    constexpr int BN = WNT * 64;   // WARPS_N = 4
    constexpr int LA = BM / 128;   // gl_lds16 per thread per A half-tile
    constexpr int LB = BN / 128;

    __shared__ __align__(16) __bf16 SH[2 * BM * 64 + 2 * BN * 64];
    __bf16(*As)[BM * 64] = (__bf16(*)[BM * 64])SH;
    __bf16(*Bs)[BN * 64] = (__bf16(*)[BN * 64])(SH + 2 * BM * 64);

    const int tid = threadIdx.x;
    const int lane = tid & 63, wave = tid >> 6;
    const int wm = wave >> 2, wn = wave & 3;
    const int quad = lane >> 4, mrow = lane & 15;

    // T1 bijective XCD swizzle (nwg % 8 == 0 for all instantiations).
    const int nbx = gridDim.x;
    const int nwg = nbx * gridDim.y;
    const int orig = (int)blockIdx.y * nbx + (int)blockIdx.x;
    const int wg = (orig & 7) * (nwg >> 3) + (orig >> 3);
    const size_t row0 = (size_t)(wg / nbx) * BM;
    const size_t col0 = (size_t)(wg % nbx) * BN;

    // Inverse-swizzled global source offsets for linear gl_lds staging.
    size_t sA[LA], sB[LB];
    int dA[LA], dB[LB];
#pragma unroll
    for (int c = 0; c < LA; ++c) {
        int q = c * 512 + tid;
        int a = q * 16;                       // linear LDS byte offset
        int p = (a >> 4) & 63;                // slot within 1024B subtile
        int rowl = (a >> 11) * 16 + (p >> 2);
        int g = (p & 3) ^ ((p >> 3) & 3);     // logical k-group at this slot
        int col = ((a >> 10) & 1) * 32 + g * 8;
        sA[c] = (size_t)rowl * ldA + col;
        dA[c] = q * 8;
    }
#pragma unroll
    for (int c = 0; c < LB; ++c) {
        int q = c * 512 + tid;
        int a = q * 16;
        int p = (a >> 4) & 63;
        int rowl = (a >> 11) * 16 + (p >> 2);
        int g = (p & 3) ^ ((p >> 3) & 3);
        int col = ((a >> 10) & 1) * 32 + g * 8;
        sB[c] = (size_t)rowl * K + col;
        dB[c] = q * 8;
    }

    const __bf16* Ag = A + row0 * ldA;
    const __bf16* Bg = B + col0 * K;

    f32x4 acc[WMT][WNT];
#pragma unroll
    for (int i = 0; i < WMT; ++i)
#pragma unroll
        for (int j = 0; j < WNT; ++j) acc[i][j] = (f32x4){0.f, 0.f, 0.f, 0.f};

    // Bank-balanced per-lane ds_read base (slot = mrow*4 + quad^((mrow>>1)&3)).
    const int abase = mrow * 64 + ((quad ^ ((mrow >> 1) & 3)) * 16);

    bf16x8 af[WMT / 2][2], af2[WMT / 2][2], bf[WNT / 2][2];

#define STA8(buf, h, kt)                                                        \
    _Pragma("unroll") for (int c = 0; c < LA; ++c)                              \
        gl_lds16(Ag + (size_t)(h) * (BM / 2) * ldA + (size_t)(kt) * 64 + sA[c], \
                 &As[buf][(h) * (BM / 2) * 64 + dA[c]])

#define STB8(buf, h, kt)                                                        \
    _Pragma("unroll") for (int c = 0; c < LB; ++c)                              \
        gl_lds16(Bg + (size_t)(h) * (BN / 2) * K + (size_t)(kt) * 64 + sB[c],   \
                 &Bs[buf][(h) * (BN / 2) * 64 + dB[c]])

#define LDA8(dst, buf, mh)                                                      \
    _Pragma("unroll") for (int m2 = 0; m2 < WMT / 2; ++m2)                      \
    _Pragma("unroll") for (int s = 0; s < 2; ++s)                               \
        dst[m2][s] = *(const bf16x8*)((const char*)&As[buf][0] +                \
            ((((mh) * (WMT / 2) + m2) * 2 + wm) * 2 + s) * 1024 + abase)

#define LDB8(buf, nh)                                                           \
    _Pragma("unroll") for (int n2 = 0; n2 < WNT / 2; ++n2)                      \
    _Pragma("unroll") for (int s = 0; s < 2; ++s)                               \
        bf[n2][s] = *(const bf16x8*)((const char*)&Bs[buf][0] +                 \
            ((((nh) * (WNT / 2) + n2) * 4 + wn) * 2 + s) * 1024 + abase)

// 8-MFMA cluster: one N-half (nh), both M-halves (af = mh0, af2 = mh1).
#define MMA16(nh)                                                               \
    _Pragma("unroll") for (int m2 = 0; m2 < WMT / 2; ++m2)                      \
    _Pragma("unroll") for (int n2 = 0; n2 < WNT / 2; ++n2)                      \
    _Pragma("unroll") for (int s = 0; s < 2; ++s) {                             \
        acc[m2][(nh) * (WNT / 2) + n2] =                                        \
            __builtin_amdgcn_mfma_f32_16x16x32_bf16(                            \
                af[m2][s], bf[n2][s],                                           \
                acc[m2][(nh) * (WNT / 2) + n2], 0, 0, 0);                       \
        acc[(WMT / 2) + m2][(nh) * (WNT / 2) + n2] =                            \
            __builtin_amdgcn_mfma_f32_16x16x32_bf16(                            \
                af2[m2][s], bf[n2][s],                                          \
                acc[(WMT / 2) + m2][(nh) * (WNT / 2) + n2], 0, 0, 0);           \
    }

#define BAR8 __builtin_amdgcn_s_barrier()

#define PHASE_TAIL(nh)                                                          \
    __builtin_amdgcn_s_barrier();                                               \
    asm volatile("s_waitcnt lgkmcnt(0)" ::: "memory");                          \
    __builtin_amdgcn_sched_barrier(0);                                          \
    __builtin_amdgcn_s_setprio(1);                                              \
    MMA16(nh);                                                                  \
    __builtin_amdgcn_s_setprio(0)

    const int NT = K / 64;

    // Prologue: tile0 full (A0h0,A0h1,B0h0,B0h1) + tile1 A halves.
    STA8(0, 0, 0);
    STA8(0, 1, 0);
    STB8(0, 0, 0);
    STB8(0, 1, 0);
    STA8(1, 0, 1);
    STA8(1, 1, 1);
    asm volatile("s_waitcnt vmcnt(3)" ::: "memory");
    BAR8;

    for (int i = 0; i < NT / 2; ++i) {
        const int u = 2 * i;
        const int k2 = (u + 2 < NT) ? u + 2 : NT - 1;
        const int k3 = (u + 3 < NT) ? u + 3 : NT - 1;
        // ---- PhA: tile u, N-half 0 ----
        LDA8(af, 0, 0); LDA8(af2, 0, 1); LDB8(0, 0);
        STB8(1, 0, u + 1); STB8(1, 1, u + 1);
        PHASE_TAIL(0);
        asm volatile("s_waitcnt vmcnt(4)" ::: "memory"); BAR8;
        // ---- PhB: tile u, N-half 1 ----
        LDB8(0, 1);
        STA8(0, 0, k2); STA8(0, 1, k2); STB8(0, 0, k2);
        PHASE_TAIL(1);
        asm volatile("s_waitcnt vmcnt(4)" ::: "memory"); BAR8;
        // ---- PhC: tile u+1, N-half 0 ----
        LDA8(af, 1, 0); LDA8(af2, 1, 1); LDB8(1, 0);
        STB8(0, 1, k2);
        PHASE_TAIL(0);
        asm volatile("s_waitcnt vmcnt(4)" ::: "memory"); BAR8;
        // ---- PhD: tile u+1, N-half 1 ----
        LDB8(1, 1);
        STA8(1, 0, k3); STA8(1, 1, k3);
        PHASE_TAIL(1);
        asm volatile("s_waitcnt vmcnt(3)" ::: "memory"); BAR8;
    }
    asm volatile("s_waitcnt vmcnt(0)" ::: "memory");

#undef STA8
#undef STB8
#undef LDA8
#undef LDB8
#undef MMA16
#undef BAR8
#undef PHASE_TAIL

    if constexpr (EPI) {
        int xblk = (int)(col0 >> 7);  // BN=128: one head per tile
        if (xblk == 24) {
            // ---- fused gate: sigmoid(x . wg^T + bg) -> gateb ----
            if (wn == 0) {
                int h = mrow;
                float bias = bg[h];
#pragma unroll
                for (int mt = 0; mt < WMT; ++mt) {
                    int rbase = (int)row0 + (mt * 2 + wm) * 16 + quad * 4;
#pragma unroll
                    for (int r = 0; r < 4; ++r) {
                        int row = rbase + r;
                        int s_ = row & 2047, b_ = row >> 11;
                        float z = acc[mt][0][r] + bias;
                        gateb[((size_t)b_ * 16 + h) * 2048 + s_] =
                            1.f / (1.f + __expf(-z));
                    }
                }
            }
            return;  // no C write (cols >= ldC)
        }
        if (xblk >= 20) {
            // ---- fused V transpose -> Vt[b][kv][d][s] (mid eliminated) ----
            int kvh = xblk - 20;
            __syncthreads();  // main-loop LDS quiescent; reuse SH
            __bf16* T = SH;   // [128][136] bf16 = 34816 B (pad keeps 16B align)
            const int d0 = wn * 16 + mrow;
#pragma unroll
            for (int mt = 0; mt < WMT; ++mt)
#pragma unroll
                for (int nt = 0; nt < WNT; ++nt) {
                    int s_loc = (mt * 2 + wm) * 16 + quad * 4;
                    int d = nt * 64 + d0;
                    __bf16* p = &T[d * 136 + s_loc];
                    p[0] = (__bf16)fin(acc[mt][nt][0]);
                    p[1] = (__bf16)fin(acc[mt][nt][1]);
                    p[2] = (__bf16)fin(acc[mt][nt][2]);
                    p[3] = (__bf16)fin(acc[mt][nt][3]);
                }
            __syncthreads();
            int d = tid >> 2, sq = (tid & 3) * 32;
            int b_ = (int)(row0 >> 11);
            int srow = (int)(row0 & 2047) + sq;
            __bf16* dst = Vt + ((size_t)(b_ * 4 + kvh) * 128 + d) * 2048 + srow;
            const __bf16* src = &T[d * 136 + sq];
#pragma unroll
            for (int c = 0; c < 4; ++c)
                *(bf16x8*)(dst + c * 8) = *(const bf16x8*)(src + c * 8);
            return;  // V never lands in qkv
        }
        {
            // ---- fused Q/K normrope from fp32 accumulators ----
            __syncthreads();  // LDS quiescent; reuse As for the reduce
            float* sums = (float*)&As[0][0];  // [wm][mt][quad][wn][r] = 512 f32
            const int d0 = wn * 16 + mrow;
#pragma unroll
            for (int mt = 0; mt < WMT; ++mt) {
                f32x4 p;
#pragma unroll
                for (int r = 0; r < 4; ++r)
                    p[r] = acc[mt][0][r] * acc[mt][0][r] +
                           acc[mt][1][r] * acc[mt][1][r];
#pragma unroll
                for (int m = 1; m < 16; m <<= 1)
#pragma unroll
                    for (int r = 0; r < 4; ++r) p[r] += __shfl_xor(p[r], m);
                if (mrow == 0) {
                    int idx = (((wm * 4 + mt) * 4 + quad) * 4 + wn) * 4;
#pragma unroll
                    for (int r = 0; r < 4; ++r) sums[idx + r] = p[r];
                }
            }
            __syncthreads();
            const bool isQ = (xblk < 16);
            const float* w = isQ ? qw : kw;
            float w1 = w[d0], w2 = w[d0 + 64];
            float osc = isQ ? SCALE_LOG2E : 1.0f;
            int kvh = xblk - 16;
#pragma unroll
            for (int mt = 0; mt < WMT; ++mt) {
                int rbase = (int)row0 + (mt * 2 + wm) * 16 + quad * 4;
                int ib = ((wm * 4 + mt) * 4 + quad) * 16;
                f32x4 sv = *(const f32x4*)&sums[ib] + *(const f32x4*)&sums[ib + 4] +
                           *(const f32x4*)&sums[ib + 8] + *(const f32x4*)&sums[ib + 12];
#pragma unroll
                for (int r = 0; r < 4; ++r) {
                    int row = rbase + r;
                    int s_ = row & 2047, b_ = row >> 11;
                    float inv = rsqrtf(sv[r] * (1.0f / 128.0f) + 1e-5f);
                    float2 cs = ropet[s_ * 64 + d0];
                    float y1 = acc[mt][0][r] * inv * w1;
                    float y2 = acc[mt][1][r] * inv * w2;
                    float v1 = (y1 * cs.x - y2 * cs.y) * osc;
                    float v2 = (y1 * cs.y + y2 * cs.x) * osc;
                    if (isQ) {
                        size_t base = (size_t)row * ldC + col0 + d0;
                        C[base] = (TC)v1;
                        C[base + 64] = (TC)v2;
                    } else {
                        __bf16* dst = Kx + (((size_t)(b_ * 4 + kvh) * 2048 + s_) << 7);
                        dst[d0] = (__bf16)v1;
                        dst[d0 + 64] = (__bf16)v2;
                    }
                }
            }
            return;  // K never written to qkv; Q written normed in place
        }
    }

#pragma unroll
    for (int mt = 0; mt < WMT; ++mt)
#pragma unroll
        for (int nt = 0; nt < WNT; ++nt)
#pragma unroll
            for (int r = 0; r < 4; ++r) {
                size_t row = row0 + (mt * 2 + wm) * 16 + quad * 4 + r;
                size_t col = col0 + (nt * 4 + wn) * 16 + mrow;
                C[row * ldC + col] = (TC)fin(acc[mt][nt][r]);
            }
}

// ---------------------------------------------------------------------------
// Flash attention v10 (unchanged from round 12): P-swizzle, MFMA-ones row
// sums, key-split-in-block, conflict-free merge; Q from qkv (stride 3072),
// O written in place over the block's own Q region.
// ---------------------------------------------------------------------------
#define FIXED_M 20.0f

#define MFMA16(a, b, c) __builtin_amdgcn_mfma_f32_16x16x32_bf16(a, b, c, 0, 0, 0)

__device__ __forceinline__ int pswz(int e) { return e ^ (((e >> 7) & 1) << 4); }

template <int MODE>  // 0: both full; 1: h0 diag + h1 full; 2: h1 diag only
__device__ __forceinline__ void attn_step(const __bf16* Kl, const __bf16* Vl,
                                          int ws, int quad, int mrow,
                                          const bf16x8* aq0, const bf16x8* aq1,
                                          f32x4* o0, f32x4* o1,
                                          f32x4& lf0, f32x4& lf1,
                                          __bf16* Pw) {
    bf16x8 ones;
#pragma unroll
    for (int i = 0; i < 8; ++i) ones[i] = (__bf16)1.0f;

    f32x4 sc0[4], sc1[4];
    __builtin_amdgcn_s_setprio(1);
#pragma unroll
    for (int jt = 0; jt < 4; ++jt) {
        f32x4 s0 = (f32x4){0.f, 0.f, 0.f, 0.f};
        f32x4 s1 = (f32x4){0.f, 0.f, 0.f, 0.f};
#pragma unroll
        for (int dt = 0; dt < 4; ++dt) {
            bf16x8 bk = *(const bf16x8*)&Kl[((dt * 4 + quad) * 64 + jt * 16 + mrow) * 8];
            if (MODE < 2) s0 = MFMA16(aq0[dt], bk, s0);
            s1 = MFMA16(aq1[dt], bk, s1);
        }
        sc0[jt] = s0;
        sc1[jt] = s1;
    }
    __builtin_amdgcn_s_setprio(0);

    if (MODE == 1) {
        int rloc = ws * 16 + quad * 4;
#pragma unroll
        for (int jt = 0; jt < 4; ++jt)
#pragma unroll
            for (int r = 0; r < 4; ++r)
                if (jt * 16 + mrow > rloc + r) sc0[jt][r] = -1e30f;
    }
    if (MODE == 2) {
        int rloc = ws * 16 + quad * 4;
#pragma unroll
        for (int jt = 0; jt < 4; ++jt)
#pragma unroll
            for (int r = 0; r < 4; ++r)
                if (jt * 16 + mrow > rloc + r) sc1[jt][r] = -1e30f;
    }

    // Streaming softmax through the SHARED per-wave P buffer (h0 then h1;
    // same-wave DS ops execute in order, so the WAR on Pw is safe).
    const int rb0 = pswz(((0 * 4 + quad) * 16 + mrow) * 8);
    const int rb1 = pswz(((1 * 4 + quad) * 16 + mrow) * 8);
    bf16x8 ap0[2], ap1[2];
    if (MODE < 2) {
#pragma unroll
        for (int jt = 0; jt < 4; ++jt)
#pragma unroll
            for (int r = 0; r < 4; ++r) {
                float pv = exp2f(sc0[jt][r] - FIXED_M);
                int k = jt * 16 + mrow;
                Pw[pswz(((k >> 3) * 16 + quad * 4 + r) * 8 + (k & 7))] = (__bf16)pv;
            }
        ap0[0] = *(const bf16x8*)&Pw[rb0];
        ap0[1] = *(const bf16x8*)&Pw[rb1];
        lf0 = MFMA16(ap0[0], ones, lf0);
        lf0 = MFMA16(ap0[1], ones, lf0);
    }
#pragma unroll
    for (int jt = 0; jt < 4; ++jt)
#pragma unroll
        for (int r = 0; r < 4; ++r) {
            float pv = exp2f(sc1[jt][r] - FIXED_M);
            int k = jt * 16 + mrow;
            Pw[pswz(((k >> 3) * 16 + quad * 4 + r) * 8 + (k & 7))] = (__bf16)pv;
        }
    ap1[0] = *(const bf16x8*)&Pw[rb0];
    ap1[1] = *(const bf16x8*)&Pw[rb1];
    lf1 = MFMA16(ap1[0], ones, lf1);
    lf1 = MFMA16(ap1[1], ones, lf1);

    __builtin_amdgcn_s_setprio(1);
#pragma unroll
    for (int d2 = 0; d2 < 8; ++d2)
#pragma unroll
        for (int ks = 0; ks < 2; ++ks) {
            bf16x8 bv = *(const bf16x8*)&Vl[((ks * 4 + quad) * 128 + d2 * 16 + mrow) * 8];
            if (MODE < 2) o0[d2] = MFMA16(ap0[ks], bv, o0[d2]);
            o1[d2] = MFMA16(ap1[ks], bv, o1[d2]);
        }
    __builtin_amdgcn_s_setprio(0);
}

__global__ __launch_bounds__(512, 2) void attn_kernel(__bf16* __restrict__ qkvO,
                                                      const __bf16* __restrict__ Kx,
                                                      const __bf16* __restrict__ Vt,
                                                      const float* __restrict__ gate) {
    __shared__ __align__(16) __bf16 Kl[2][2][64 * 128];  // [stream][buf]
    __shared__ __align__(16) __bf16 Vl[2][2][128 * 64];  // [stream][buf]
    __shared__ __align__(16) __bf16 Pl[8][1024];
    int tid = threadIdx.x, lane = tid & 63, wave = tid >> 6;

    int ws = wave & 3, st = wave >> 2;  // row-group, stream
    int quad = lane >> 4, mrow = lane & 15;
    __bf16* Pw = &Pl[wave][0];

    int idx = blockIdx.x;
    int qb = 15 - (idx >> 5);  // longest items dispatch first (backfill)
    int h = idx & 15, b = (idx >> 4) & 1;
    int kvh = h >> 2;

    // Staging: threads 0-255 stage the even-stream tile, 256-511 the odd.
    int sst = tid >> 8, lt = tid & 255;
    const __bf16* kbase = Kx + (size_t)(b * 4 + kvh) * 2048 * 128 + (lt & 63) * 128 + (lt >> 6) * 8;
    const __bf16* vbase = Vt + (size_t)(b * 4 + kvh) * 128 * 2048 + (lt & 127) * 2048 + (lt >> 7) * 8;
    int ldst = lt * 8;

    auto STAGE = [&](int buf, int tile) {
        const __bf16* kp = kbase + (size_t)tile * 8192;
        const __bf16* vp = vbase + (size_t)tile * 64;
#pragma unroll
        for (int c = 0; c < 4; ++c) gl_lds16(kp + 32 * c, &Kl[sst][buf][ldst + 2048 * c]);
#pragma unroll
        for (int c = 0; c < 4; ++c) gl_lds16(vp + 16 * c, &Vl[sst][buf][ldst + 2048 * c]);
    };

    STAGE(0, sst);  // even stream: tile 0; odd stream: tile 1

    // Q from qkv (normed+roped in the gemm epilogue), row stride 3072.
    const __bf16* Qh = qkvO + (size_t)(b * 2048 + qb * 128 + ws * 16 + mrow) * 3072 + h * 128;
    bf16x8 aq0[4], aq1[4];
#pragma unroll
    for (int dt = 0; dt < 4; ++dt) {
        aq0[dt] = *(const bf16x8*)(Qh + dt * 32 + quad * 8);
        aq1[dt] = *(const bf16x8*)(Qh + (size_t)64 * 3072 + dt * 32 + quad * 8);
    }

    f32x4 o0[8], o1[8];
#pragma unroll
    for (int d2 = 0; d2 < 8; ++d2) {
        o0[d2] = (f32x4){0.f, 0.f, 0.f, 0.f};
        o1[d2] = (f32x4){0.f, 0.f, 0.f, 0.f};
    }
    f32x4 lf0 = (f32x4){0.f, 0.f, 0.f, 0.f}, lf1 = (f32x4){0.f, 0.f, 0.f, 0.f};

    __syncthreads();  // tiles 0,1 visible (barrier drains gl_lds)

    int cur = 0;
    for (int kt = 0; kt < qb; ++kt) {
        STAGE(cur ^ 1, 2 * (kt + 1) + sst);  // prefetch both streams' next
        attn_step<0>(Kl[st][cur], Vl[st][cur], ws, quad, mrow, aq0, aq1, o0, o1, lf0, lf1, Pw);
        __syncthreads();
        cur ^= 1;
    }
    // Last step: even stream tile 2qb = MODE1; odd stream tile 2qb+1 = MODE2.
    if (st == 0)
        attn_step<1>(Kl[0][cur], Vl[0][cur], ws, quad, mrow, aq0, aq1, o0, o1, lf0, lf1, Pw);
    else
        attn_step<2>(Kl[1][cur], Vl[1][cur], ws, quad, mrow, aq0, aq1, o0, o1, lf0, lf1, Pw);

    // ---- in-block fp32 merge, conflict-free [slot][lane] layout ----
    __syncthreads();  // all waves done with K/V LDS
    f32x4* mo = (f32x4*)&Kl[0][0][0];   // 16 slots x 256 lanes x f32x4 = 64 KB
    float* ml = (float*)&Pl[0][0];      // 8 slots x 256 lanes x f32 = 8 KB
    int mlane = ws * 64 + lane;
    if (st == 1) {
#pragma unroll
        for (int d2 = 0; d2 < 8; ++d2) {
            mo[d2 * 256 + mlane] = o0[d2];
            mo[(d2 + 8) * 256 + mlane] = o1[d2];
        }
#pragma unroll
        for (int r = 0; r < 4; ++r) {
            ml[r * 256 + mlane] = lf0[r];
            ml[(r + 4) * 256 + mlane] = lf1[r];
        }
    }
    __syncthreads();
    if (st == 0) {
#pragma unroll
        for (int d2 = 0; d2 < 8; ++d2) {
            o0[d2] += mo[d2 * 256 + mlane];
            o1[d2] += mo[(d2 + 8) * 256 + mlane];
        }
#pragma unroll
        for (int r = 0; r < 4; ++r) {
            lf0[r] += ml[r * 256 + mlane];
            lf1[r] += ml[(r + 4) * 256 + mlane];
        }
#pragma unroll
        for (int hf = 0; hf < 2; ++hf) {
            f32x4* oo = hf ? o1 : o0;
            f32x4 ll = hf ? lf1 : lf0;
            int srow0 = qb * 128 + hf * 64 + ws * 16 + quad * 4;
            float gv[4], il[4];
#pragma unroll
            for (int r = 0; r < 4; ++r) {
                gv[r] = gate[((size_t)b * 16 + h) * 2048 + srow0 + r];
                il[r] = 1.0f / fmaxf(ll[r], 1e-30f);
            }
            // O in place over this block's own Q region (stride 3072).
#pragma unroll
            for (int d2 = 0; d2 < 8; ++d2)
#pragma unroll
                for (int r = 0; r < 4; ++r)
                    qkvO[(size_t)(b * 2048 + srow0 + r) * 3072 + h * 128 + d2 * 16 + mrow] =
                        (__bf16)fin(oo[d2][r] * il[r] * gv[r]);
        }
    }
}

// ---------------------------------------------------------------------------
// Memory plan (ws <= 33,554,432 B; d_out doubles as scratch where safe).
//   d_out: xb[0,16.7M) + wqb[16.7M,29.88M) (3200 rows: w_qkv + w_gate pad) +
//          gateb[29.88M,+256K) + ropet[30.15M,+1M) -> out fp32 [0,33.5M)
//   ws: qkv[0,25.2M): Q-cols normed by gQKV epi, overwritten in place by
//       attn's O; V/K col ranges never written. Kb[25.2,29.4M) /
//       Vtb[29.4,33.5M) written by the gemmQKV epilogue, live through attn,
//       then wob over [25.2,33.5M) (wo_cvt after attn).
// Launch graph (5): prep -> gemmQKV(+Q/K/V/gate-epi, N=3200 ldC=3072) ->
//                   attn -> wo_cvt -> gemmOut(A=qkv ldA=3072)
// ---------------------------------------------------------------------------
extern "C" void kernel_launch(void* const* d_in, const int* in_sizes, int n_in,
                              void* d_out, int out_size, void* d_ws, size_t ws_size,
                              hipStream_t stream) {
    const float* x = (const float*)d_in[0];
    const float* w_qkv = (const float*)d_in[1];
    const float* q_norm_w = (const float*)d_in[2];
    const float* k_norm_w = (const float*)d_in[3];
    const float* w_gate = (const float*)d_in[4];
    const float* b_gate = (const float*)d_in[5];
    const float* w_o = (const float*)d_in[6];
    float* out = (float*)d_out;

    char* ws = (char*)d_ws;
    char* od = (char*)d_out;
    __bf16* xb = (__bf16*)(od);
    __bf16* wqb = (__bf16*)(od + 16777216);
    float* gateb = (float*)(od + 29884416);
    float2* ropet = (float2*)(od + 30146560);
    __bf16* qkv = (__bf16*)(ws);
    __bf16* Kb = (__bf16*)(ws + 25165824);
    __bf16* Vtb = (__bf16*)(ws + 29360128);
    __bf16* wob = (__bf16*)(ws + 25165824);  // over Kb+Vtb, dead post-attn

    // prep: cvt x [0,4096) + cvt w_qkv [4096,7168) + cvt w_gate [7168,7184)
    //       + rope table [7184,7696)
    prep_kernel<<<7696, 256, 0, stream>>>(x, w_qkv, w_gate, xb, wqb, ropet);
    // QKV+gate GEMM: 128x128 tile, grid 25x32 = 800 blocks; Q normed in
    // place, K -> Kb, V transposed -> Vtb, gate -> gateb.
    gemm8p<4, 2, 1, __bf16><<<dim3(3200 / 128, 4096 / 128), 512, 0, stream>>>(
        xb, wqb, qkv, 4096, 3200, 2048, 2048, 3072,
        q_norm_w, k_norm_w, ropet, Kb, b_gate, gateb, Vtb);
    // attn: Q from qkv, O in place over Q
    attn_kernel<<<512, 512, 0, stream>>>(qkv, Kb, Vtb, gateb);
    // w_o cvt into the dead Kb/Vtb region
    wo_cvt_kernel<<<2048, 256, 0, stream>>>(w_o, wob);
    // Output GEMM: 128x128 tile, grid 16x32 = 512 blocks; A = qkv ldA=3072.
    gemm8p<4, 2, 0, float><<<dim3(2048 / 128, 4096 / 128), 512, 0, stream>>>(
        qkv, wob, out, 4096, 2048, 2048, 3072, 2048,
        nullptr, nullptr, nullptr, nullptr, nullptr, nullptr, nullptr);
}